// Round 3
// baseline (12903.667 us; speedup 1.0000x reference)
//
#include <hip/hip_runtime.h>
#include <stdint.h>
#include <math.h>

typedef __attribute__((ext_vector_type(8))) short bf16x8;
typedef __attribute__((ext_vector_type(4))) float f32x4;
typedef __attribute__((ext_vector_type(4))) unsigned int u32x4;

#define BATCH 4
#define T_M 32
#define DE 128
#define T_W 2560
#define NG 224        /* wav-rnn workgroups; 896/224 = 4 units per WG */
#define RPW 12        /* gate rows per WG = 3 gates * 4 units */

__device__ __forceinline__ float b2f(unsigned short h) {
  return __uint_as_float(((unsigned int)h) << 16);
}
__device__ __forceinline__ unsigned short f2b(float f) {
  unsigned int u = __float_as_uint(f);
  u = u + 0x7fffu + ((u >> 16) & 1u);   // RNE
  return (unsigned short)(u >> 16);
}
__device__ __forceinline__ float blo(unsigned int u){ return __uint_as_float(u << 16); }
__device__ __forceinline__ float bhi(unsigned int u){ return __uint_as_float(u & 0xffff0000u); }
__device__ __forceinline__ float sigm(float x){ return 1.f / (1.f + __expf(-x)); }
__device__ __forceinline__ float gelu_exact(float x){ return 0.5f * x * (1.f + erff(x * 0.70710678118654752f)); }

// ---------------- fp32 -> bf16 cast ----------------
__global__ __launch_bounds__(256) void k_cast(const float* __restrict__ src,
                                              unsigned short* __restrict__ dst, int n)
{
  int i = blockIdx.x * 256 + threadIdx.x;
  if (i < n) dst[i] = f2b(src[i]);
}

// ---------------- encoder: input projections gi = in @ Wih^T + bih ----------------
__global__ __launch_bounds__(384) void k_gi_enc(
    const float* __restrict__ in, const float* __restrict__ Wih,
    const float* __restrict__ bih, float* __restrict__ out, int K)
{
  __shared__ float in_s[256];
  int tb = blockIdx.x;
  for (int i = threadIdx.x; i < K; i += 384) in_s[i] = in[tb * K + i];
  __syncthreads();
  int row = threadIdx.x;
  float acc = bih[row];
  const float* wr = Wih + row * K;
  for (int k = 0; k < K; ++k) acc += in_s[k] * wr[k];
  out[tb * 384 + row] = acc;
}

// ---------------- encoder: sequential scan, one WG per direction ----------------
__global__ __launch_bounds__(512) void k_scan_enc(
    const float* __restrict__ gi_f, const float* __restrict__ gi_b,
    const float* __restrict__ whh_f, const float* __restrict__ bhh_f,
    const float* __restrict__ whh_b, const float* __restrict__ bhh_b,
    float* __restrict__ c_out)   // (32,4,256)
{
  const int dir = blockIdx.x, tid = threadIdx.x;
  const float* gi  = dir ? gi_b  : gi_f;
  const float* whh = dir ? whh_b : whh_f;
  const float* bhh = dir ? bhh_b : bhh_f;
  __shared__ unsigned short h_s[BATCH][DE + 8];
  __shared__ float gh_s[384][4];
  __shared__ float bhh_s[384];
  for (int i = tid; i < 384; i += 512) bhh_s[i] = bhh[i];
  for (int i = tid; i < BATCH * (DE + 8); i += 512) ((unsigned short*)h_s)[i] = 0;
  __syncthreads();
  for (int s = 0; s < T_M; ++s) {
    int t = dir ? (T_M - 1 - s) : s;
    #pragma unroll
    for (int k3 = 0; k3 < 3; ++k3) {
      int d = tid + 512 * k3;
      int row = d >> 2, b = d & 3;
      const float* wr = whh + row * DE;
      float acc = 0.f;
      for (int j = 0; j < DE; j += 8) {
        float4 w0 = *(const float4*)(wr + j);
        float4 w1 = *(const float4*)(wr + j + 4);
        uint4  hv = *(const uint4*)&h_s[b][j];
        acc += w0.x * blo(hv.x) + w0.y * bhi(hv.x) + w0.z * blo(hv.y) + w0.w * bhi(hv.y);
        acc += w1.x * blo(hv.z) + w1.y * bhi(hv.z) + w1.z * blo(hv.w) + w1.w * bhi(hv.w);
      }
      gh_s[row][b] = acc + bhh_s[row];
    }
    __syncthreads();
    {
      int u = tid >> 2, b = tid & 3;
      const float* git = gi + (t * BATCH + b) * 384;
      float r = sigm(git[u] + gh_s[u][b]);
      float z = sigm(git[DE + u] + gh_s[DE + u][b]);
      float n = tanhf(git[2 * DE + u] + r * gh_s[2 * DE + u][b]);
      float hold = b2f(h_s[b][u]);
      float hnew = (1.f - z) * n + z * hold;
      c_out[(t * BATCH + b) * 256 + dir * DE + u] = hnew;
      h_s[b][u] = f2b(hnew);
    }
    __syncthreads();
  }
}

// ---------------- build wav-GRU input X = [embed, upsampled c] (bf16) ----------------
__global__ __launch_bounds__(256) void k_build_X(
    const float* __restrict__ y, const float* __restrict__ E,
    const float* __restrict__ c1, unsigned short* __restrict__ X)
{
  int t = blockIdx.x, c = threadIdx.x;
  int tm = t / 80;
  #pragma unroll
  for (int b = 0; b < BATCH; ++b) {
    float w = (t == 0) ? 0.f : y[(t - 1) * BATCH + b];
    int q = (int)floorf((w + 1.f) * 128.f);
    q = q < 0 ? 0 : (q > 255 ? 255 : q);
    unsigned short* xb = X + (size_t)(t * BATCH + b) * 512;
    xb[c]       = f2b(E[q * 256 + c]);
    xb[256 + c] = f2b(c1[(tm * BATCH + b) * 256 + c]);
  }
}

// ---------------- MFMA GEMM: C(MxN) = act(A(bf16 MxK) @ B(bf16 NxK)^T + bias) -------
__global__ __launch_bounds__(256) void k_mgemm(
    const unsigned short* __restrict__ A, const unsigned short* __restrict__ B,
    const float* __restrict__ bias, void* __restrict__ C,
    int M, int N, int K, int act, int c_bf16)
{
  __shared__ unsigned short As[128][40];
  __shared__ unsigned short Bs[128][40];
  const int tid = threadIdx.x;
  const int m0 = blockIdx.x * 128, n0 = blockIdx.y * 128;
  const int lane = tid & 63, wave = tid >> 6;
  const int wy = wave >> 1, wx = wave & 1;
  const int row16 = lane & 15, quad = lane >> 4;
  const int sr = tid >> 1, sc = (tid & 1) * 16;
  f32x4 acc[4][4] = {};
  for (int kt = 0; kt < K; kt += 32) {
    uint4 av  = *(const uint4*)(A + (size_t)(m0 + sr) * K + kt + sc);
    uint4 av2 = *(const uint4*)(A + (size_t)(m0 + sr) * K + kt + sc + 8);
    uint4 bv  = *(const uint4*)(B + (size_t)(n0 + sr) * K + kt + sc);
    uint4 bv2 = *(const uint4*)(B + (size_t)(n0 + sr) * K + kt + sc + 8);
    __syncthreads();
    *(uint4*)&As[sr][sc] = av; *(uint4*)&As[sr][sc + 8] = av2;
    *(uint4*)&Bs[sr][sc] = bv; *(uint4*)&Bs[sr][sc + 8] = bv2;
    __syncthreads();
    bf16x8 af[4], bf[4];
    #pragma unroll
    for (int i = 0; i < 4; ++i) af[i] = *(const bf16x8*)&As[wy * 64 + i * 16 + row16][quad * 8];
    #pragma unroll
    for (int j = 0; j < 4; ++j) bf[j] = *(const bf16x8*)&Bs[wx * 64 + j * 16 + row16][quad * 8];
    #pragma unroll
    for (int i = 0; i < 4; ++i)
      #pragma unroll
      for (int j = 0; j < 4; ++j)
        acc[i][j] = __builtin_amdgcn_mfma_f32_16x16x32_bf16(af[i], bf[j], acc[i][j], 0, 0, 0);
  }
  #pragma unroll
  for (int i = 0; i < 4; ++i) {
    #pragma unroll
    for (int j = 0; j < 4; ++j) {
      int col = n0 + wx * 64 + j * 16 + row16;
      float bs = bias[col];
      #pragma unroll
      for (int r = 0; r < 4; ++r) {
        int row = m0 + wy * 64 + i * 16 + quad * 4 + r;
        float v = acc[i][j][r] + bs;
        if (act) v = gelu_exact(v);
        if (c_bf16) ((unsigned short*)C)[(size_t)row * N + col] = f2b(v);
        else        ((float*)C)[(size_t)row * N + col] = v;
      }
    }
  }
}

// ---------------- wav GRU: persistent kernel, tag-in-packet sync (no barrier) --------
// h slices published as 16B packets {h0h1,h2h3,tag,pad} via single dwordx4 sc0 sc1
// stores; consumers poll packets directly. Double-buffered -> WG skew bounded to 1.
__global__ __launch_bounds__(256, 1) void k_wav_rnn(
    const float* __restrict__ whh,          // (2688,896) fp32
    const float* __restrict__ bhh,          // (2688,)
    const unsigned short* __restrict__ gi,  // (10240,2688) bf16 = X@Wih^T + bih
    unsigned int* __restrict__ hslots,      // 2*896 packets of 16B, zeroed
    unsigned int* __restrict__ O32,         // (10240,448) dwords of bf16 pairs
    int* __restrict__ unused0, int* __restrict__ unused1)
{
  const int wg = blockIdx.x, tid = threadIdx.x;
  const int lane = tid & 63, wave = tid >> 6;

  __shared__ unsigned short wcat_s[RPW][904];   // Whh rows (bf16)
  __shared__ float phh_s[4][16][4];             // [wave][row][b]
  __shared__ float bhh_s[RPW];

  for (int idx = tid; idx < RPW * 896; idx += 256) {
    int r = idx / 896, c = idx - r * 896;
    int g = r >> 2, u = r & 3;
    wcat_s[r][c] = f2b(whh[(size_t)(g * 896 + wg * 4 + u) * 896 + c]);
  }
  if (tid < RPW) bhh_s[tid] = bhh[(tid >> 2) * 896 + wg * 4 + (tid & 3)];
  __syncthreads();

  const int row16 = lane & 15;
  const int mrow = row16 < RPW ? row16 : (RPW - 1);  // clamp dup (rows 12-15 unused)
  const int bcol = row16 & 3;
  const int quad = lane >> 4;

  // lane-constant packet offsets (bytes) within a buffer
  const unsigned int loff = (unsigned int)((bcol * 224 + wave * 56 + quad * 2) << 4);
  const unsigned long long base0 = (unsigned long long)hslots;
  const unsigned long long base1 = base0 + 14336ull;

  // registers: previous h for the 16 owner lanes (wave 0, tid<16)
  float hprev = 0.f;
  float gir = 0.f, giz = 0.f, gin = 0.f;
  if (wave == 0 && tid < 16) {
    int u = tid >> 2, b = tid & 3;
    const unsigned short* g0 = gi + (size_t)b * 2688 + wg * 4 + u;
    gir = b2f(g0[0]); giz = b2f(g0[896]); gin = b2f(g0[1792]);
  }

  for (int t = 0; t < T_W; ++t) {
    const unsigned long long hb = ((t & 1) ? base1 : base0) + loff;
    unsigned long long a0 = hb,            a1 = hb + 16;
    unsigned long long a2 = hb + 128,      a3 = hb + 144;
    unsigned long long a4 = hb + 256,      a5 = hb + 272;
    unsigned long long a6 = hb + 384,      a7 = hb + 400;
    unsigned long long a8 = hb + 512,      a9 = hb + 528;
    unsigned long long a10 = hb + 640,     a11 = hb + 656;
    unsigned long long a12 = hb + 768,     a13 = hb + 784;
    u32x4 s0, s1, s2, s3, s4, s5, s6, s7, s8, s9, s10, s11, s12, s13;
    const unsigned int tg = (unsigned int)t;
    unsigned int bad;
    do {
      asm volatile(
        "global_load_dwordx4 %0, %14, off sc0 sc1\n"
        "global_load_dwordx4 %1, %15, off sc0 sc1\n"
        "global_load_dwordx4 %2, %16, off sc0 sc1\n"
        "global_load_dwordx4 %3, %17, off sc0 sc1\n"
        "global_load_dwordx4 %4, %18, off sc0 sc1\n"
        "global_load_dwordx4 %5, %19, off sc0 sc1\n"
        "global_load_dwordx4 %6, %20, off sc0 sc1\n"
        "global_load_dwordx4 %7, %21, off sc0 sc1\n"
        "global_load_dwordx4 %8, %22, off sc0 sc1\n"
        "global_load_dwordx4 %9, %23, off sc0 sc1\n"
        "global_load_dwordx4 %10, %24, off sc0 sc1\n"
        "global_load_dwordx4 %11, %25, off sc0 sc1\n"
        "global_load_dwordx4 %12, %26, off sc0 sc1\n"
        "global_load_dwordx4 %13, %27, off sc0 sc1\n"
        "s_waitcnt vmcnt(0)"
        : "=&v"(s0), "=&v"(s1), "=&v"(s2), "=&v"(s3), "=&v"(s4), "=&v"(s5), "=&v"(s6),
          "=&v"(s7), "=&v"(s8), "=&v"(s9), "=&v"(s10), "=&v"(s11), "=&v"(s12), "=&v"(s13)
        : "v"(a0), "v"(a1), "v"(a2), "v"(a3), "v"(a4), "v"(a5), "v"(a6),
          "v"(a7), "v"(a8), "v"(a9), "v"(a10), "v"(a11), "v"(a12), "v"(a13)
        : "memory");
      bad = (s0.z ^ tg) | (s1.z ^ tg) | (s2.z ^ tg) | (s3.z ^ tg) | (s4.z ^ tg)
          | (s5.z ^ tg) | (s6.z ^ tg) | (s7.z ^ tg) | (s8.z ^ tg) | (s9.z ^ tg)
          | (s10.z ^ tg) | (s11.z ^ tg) | (s12.z ^ tg) | (s13.z ^ tg);
    } while (__any(bad != 0));

    // --- Whh . h via MFMA (28 chunks of K=32 across 4 waves) ---
    f32x4 ahh = {0.f, 0.f, 0.f, 0.f};
    #define DOCHUNK(KC, SA, SB) { \
      union { unsigned int u[4]; bf16x8 v; } bb; \
      bb.u[0] = SA.x; bb.u[1] = SA.y; bb.u[2] = SB.x; bb.u[3] = SB.y; \
      bf16x8 af = *(const bf16x8*)&wcat_s[mrow][(wave * 7 + KC) * 32 + quad * 8]; \
      ahh = __builtin_amdgcn_mfma_f32_16x16x32_bf16(af, bb.v, ahh, 0, 0, 0); }
    DOCHUNK(0, s0, s1)  DOCHUNK(1, s2, s3)  DOCHUNK(2, s4, s5)  DOCHUNK(3, s6, s7)
    DOCHUNK(4, s8, s9)  DOCHUNK(5, s10, s11) DOCHUNK(6, s12, s13)
    #undef DOCHUNK

    if (row16 < 4) {
      #pragma unroll
      for (int r = 0; r < 4; ++r) phh_s[wave][quad * 4 + r][row16] = ahh[r];
    }
    __syncthreads();

    // --- finalize 16 h values in wave 0, publish packet with tag t+1 ---
    if (wave == 0) {
      unsigned int hu = 0;
      if (tid < 16) {
        int u = tid >> 2, b = tid & 3;
        float ghr = phh_s[0][u][b] + phh_s[1][u][b] + phh_s[2][u][b] + phh_s[3][u][b] + bhh_s[u];
        float ghz = phh_s[0][4+u][b] + phh_s[1][4+u][b] + phh_s[2][4+u][b] + phh_s[3][4+u][b] + bhh_s[4+u];
        float ghn = phh_s[0][8+u][b] + phh_s[1][8+u][b] + phh_s[2][8+u][b] + phh_s[3][8+u][b] + bhh_s[8+u];
        float r = sigm(gir + ghr);
        float z = sigm(giz + ghz);
        float n = tanhf(gin + r * ghn);
        float hnew = (1.f - z) * n + z * hprev;
        hprev = hnew;
        hu = f2b(hnew);
      }
      int b4 = tid & 3;
      unsigned int u0 = (unsigned int)__shfl((int)hu, b4);
      unsigned int u1 = (unsigned int)__shfl((int)hu, 4 + b4);
      unsigned int u2 = (unsigned int)__shfl((int)hu, 8 + b4);
      unsigned int u3 = (unsigned int)__shfl((int)hu, 12 + b4);
      if (tid < 4) {
        u32x4 pkt;
        pkt.x = (u0 & 0xffffu) | (u1 << 16);
        pkt.y = (u2 & 0xffffu) | (u3 << 16);
        pkt.z = (unsigned int)(t + 1);
        pkt.w = 0u;
        // O output (plain store, flushed at kernel end)
        *(uint2*)(O32 + (size_t)(t * 4 + b4) * 448 + wg * 2) = make_uint2(pkt.x, pkt.y);
        unsigned long long sa = (((t + 1) & 1) ? base1 : base0)
                              + (unsigned long long)((b4 * 224 + wg) << 4);
        asm volatile("global_store_dwordx4 %0, %1, off sc0 sc1"
                     :: "v"(sa), "v"(pkt) : "memory");
      }
      // prefetch gi for t+1 (off critical path)
      if (tid < 16 && t + 1 < T_W) {
        int u = tid >> 2, b = tid & 3;
        const unsigned short* g0 = gi + (size_t)((t + 1) * 4 + b) * 2688 + wg * 4 + u;
        gir = b2f(g0[0]); giz = b2f(g0[896]); gin = b2f(g0[1792]);
      }
    }
    __syncthreads();   // protect phh_s for next iteration
  }
}

// ---------------- NLL ----------------
__global__ __launch_bounds__(256) void k_nll(
    const float* __restrict__ logits, const float* __restrict__ y,
    float* __restrict__ acc)
{
  int wid = threadIdx.x >> 6, lane = threadIdx.x & 63;
  int row = blockIdx.x * 4 + wid;
  const float* lr = logits + (size_t)row * 256;
  float v0 = lr[lane], v1 = lr[lane + 64], v2 = lr[lane + 128], v3 = lr[lane + 192];
  float mx = fmaxf(fmaxf(v0, v1), fmaxf(v2, v3));
  for (int off = 32; off > 0; off >>= 1) mx = fmaxf(mx, __shfl_xor(mx, off));
  float se = __expf(v0 - mx) + __expf(v1 - mx) + __expf(v2 - mx) + __expf(v3 - mx);
  for (int off = 32; off > 0; off >>= 1) se += __shfl_xor(se, off);
  if (lane == 0) {
    float w = y[row];
    int q = (int)floorf((w + 1.f) * 128.f);
    q = q < 0 ? 0 : (q > 255 ? 255 : q);
    float contrib = (logf(se) + mx) - lr[q];
    atomicAdd(acc, contrib);
  }
}

__global__ void k_final(const float* __restrict__ acc, float* __restrict__ out) {
  out[0] = acc[0] * (1.f / 10240.f);
}

// ---------------- host ----------------
extern "C" void kernel_launch(void* const* d_in, const int* in_sizes, int n_in,
                              void* d_out, int out_size, void* d_ws, size_t ws_size,
                              hipStream_t stream)
{
  const float* x       = (const float*)d_in[0];
  const float* y       = (const float*)d_in[1];
  const float* m0f_Wih = (const float*)d_in[2];
  const float* m0f_Whh = (const float*)d_in[3];
  const float* m0f_bih = (const float*)d_in[4];
  const float* m0f_bhh = (const float*)d_in[5];
  const float* m0b_Wih = (const float*)d_in[6];
  const float* m0b_Whh = (const float*)d_in[7];
  const float* m0b_bih = (const float*)d_in[8];
  const float* m0b_bhh = (const float*)d_in[9];
  const float* m1f_Wih = (const float*)d_in[10];
  const float* m1f_Whh = (const float*)d_in[11];
  const float* m1f_bih = (const float*)d_in[12];
  const float* m1f_bhh = (const float*)d_in[13];
  const float* m1b_Wih = (const float*)d_in[14];
  const float* m1b_Whh = (const float*)d_in[15];
  const float* m1b_bih = (const float*)d_in[16];
  const float* m1b_bhh = (const float*)d_in[17];
  const float* w_Wih   = (const float*)d_in[18];
  const float* w_Whh   = (const float*)d_in[19];
  const float* w_bih   = (const float*)d_in[20];
  const float* w_bhh   = (const float*)d_in[21];
  const float* Wp      = (const float*)d_in[22];
  const float* bp      = (const float*)d_in[23];
  const float* E       = (const float*)d_in[24];
  const float* Wd      = (const float*)d_in[25];
  const float* bd      = (const float*)d_in[26];

  char* ws = (char*)d_ws;
  size_t off = 0;
  auto alloc = [&](size_t bytes) -> void* {
    void* p = ws + off;
    off += (bytes + 255) & ~(size_t)255;
    return p;
  };
  // misc (zeroed each launch): nll acc + h packet buffers
  float*        nacc   = (float*)alloc(64);
  unsigned int* hslots = (unsigned int*)alloc(2 * 896 * 16);
  size_t misc_bytes = off;

  float* c0   = (float*)alloc((size_t)32 * 4 * 256 * 4);
  float* c1   = (float*)alloc((size_t)32 * 4 * 256 * 4);
  float* gi0f = (float*)alloc((size_t)32 * 4 * 384 * 4);
  float* gi0b = (float*)alloc((size_t)32 * 4 * 384 * 4);
  float* gi1f = (float*)alloc((size_t)32 * 4 * 384 * 4);
  float* gi1b = (float*)alloc((size_t)32 * 4 * 384 * 4);
  unsigned short* X     = (unsigned short*)alloc((size_t)10240 * 512 * 2);
  unsigned short* gi_w  = (unsigned short*)alloc((size_t)10240 * 2688 * 2);
  unsigned int*   O32   = (unsigned int*)alloc((size_t)10240 * 448 * 4);
  unsigned short* O2    = (unsigned short*)alloc((size_t)10240 * 512 * 2);
  float*          LG    = (float*)alloc((size_t)10240 * 256 * 4);
  unsigned short* Wih_b = (unsigned short*)alloc((size_t)2688 * 512 * 2);
  unsigned short* Wp_b  = (unsigned short*)alloc((size_t)512 * 896 * 2);
  unsigned short* Wd_b  = (unsigned short*)alloc((size_t)256 * 512 * 2);

  hipMemsetAsync(d_ws, 0, misc_bytes, stream);

  // weight casts
  k_cast<<<(2688 * 512 + 255) / 256, 256, 0, stream>>>(w_Wih, Wih_b, 2688 * 512);
  k_cast<<<(512 * 896 + 255) / 256, 256, 0, stream>>>(Wp, Wp_b, 512 * 896);
  k_cast<<<(256 * 512 + 255) / 256, 256, 0, stream>>>(Wd, Wd_b, 256 * 512);

  // encoder
  k_gi_enc<<<128, 384, 0, stream>>>(x, m0f_Wih, m0f_bih, gi0f, 80);
  k_gi_enc<<<128, 384, 0, stream>>>(x, m0b_Wih, m0b_bih, gi0b, 80);
  k_scan_enc<<<2, 512, 0, stream>>>(gi0f, gi0b, m0f_Whh, m0f_bhh, m0b_Whh, m0b_bhh, c0);
  k_gi_enc<<<128, 384, 0, stream>>>(c0, m1f_Wih, m1f_bih, gi1f, 256);
  k_gi_enc<<<128, 384, 0, stream>>>(c0, m1b_Wih, m1b_bih, gi1b, 256);
  k_scan_enc<<<2, 512, 0, stream>>>(gi1f, gi1b, m1f_Whh, m1f_bhh, m1b_Whh, m1b_bhh, c1);

  // wav input + precomputed input projection (includes bih)
  k_build_X<<<2560, 256, 0, stream>>>(y, E, c1, X);
  k_mgemm<<<dim3(80, 21), 256, 0, stream>>>(X, Wih_b, w_bih, (void*)gi_w,
                                            10240, 2688, 512, 0, 1);

  // recurrent wav GRU (persistent, tag-based sync; all 224 WGs resident)
  k_wav_rnn<<<NG, 256, 0, stream>>>(w_Whh, w_bhh, gi_w, hslots, O32,
                                    (int*)nullptr, (int*)nullptr);

  // head
  k_mgemm<<<dim3(80, 4), 256, 0, stream>>>((const unsigned short*)O32, Wp_b, bp,
                                           (void*)O2, 10240, 512, 896, 1, 1);
  k_mgemm<<<dim3(80, 2), 256, 0, stream>>>(O2, Wd_b, bd, (void*)LG,
                                           10240, 256, 512, 0, 0);
  k_nll<<<2560, 256, 0, stream>>>(LG, y, nacc);
  k_final<<<1, 1, 0, stream>>>(nacc, (float*)d_out);
}

// Round 4
// 8859.229 us; speedup vs baseline: 1.4565x; 1.4565x over previous
//
#include <hip/hip_runtime.h>
#include <stdint.h>
#include <math.h>

typedef __attribute__((ext_vector_type(8))) short bf16x8;
typedef __attribute__((ext_vector_type(4))) float f32x4;
typedef __attribute__((ext_vector_type(4))) unsigned int u32x4;

#define BATCH 4
#define T_M 32
#define DE 128
#define T_W 2560
#define NGW 56        /* wav-rnn workgroups; 896/56 = 16 units per WG */

__device__ __forceinline__ float b2f(unsigned short h) {
  return __uint_as_float(((unsigned int)h) << 16);
}
__device__ __forceinline__ unsigned short f2b(float f) {
  unsigned int u = __float_as_uint(f);
  u = u + 0x7fffu + ((u >> 16) & 1u);   // RNE
  return (unsigned short)(u >> 16);
}
__device__ __forceinline__ float blo(unsigned int u){ return __uint_as_float(u << 16); }
__device__ __forceinline__ float bhi(unsigned int u){ return __uint_as_float(u & 0xffff0000u); }
__device__ __forceinline__ float sigm(float x){ return 1.f / (1.f + __expf(-x)); }
__device__ __forceinline__ float gelu_exact(float x){ return 0.5f * x * (1.f + erff(x * 0.70710678118654752f)); }

// ---------------- fp32 -> bf16 cast ----------------
__global__ __launch_bounds__(256) void k_cast(const float* __restrict__ src,
                                              unsigned short* __restrict__ dst, int n)
{
  int i = blockIdx.x * 256 + threadIdx.x;
  if (i < n) dst[i] = f2b(src[i]);
}

// ---------------- pre-swizzle Whh into MFMA A-fragment order ----------------
// out[(((wg*3+g)*28+kc)*4+quad)*16+row16)*8+j] = whh[(g*896+wg*16+row16)*896 + kc*32+quad*8+j]
__global__ __launch_bounds__(256) void k_prep_whh(const float* __restrict__ whh,
                                                  unsigned short* __restrict__ out)
{
  int idx = blockIdx.x * 256 + threadIdx.x;
  if (idx >= NGW * 3 * 28 * 4 * 16 * 8) return;
  int j     = idx & 7;
  int row16 = (idx >> 3) & 15;
  int quad  = (idx >> 7) & 3;
  int kc    = (idx >> 9) % 28;
  int rest  = (idx >> 9) / 28;     // wg*3 + g
  int g = rest % 3, wg = rest / 3;
  int grow = g * 896 + wg * 16 + row16;
  int col  = kc * 32 + quad * 8 + j;
  out[idx] = f2b(whh[(size_t)grow * 896 + col]);
}

// ---------------- encoder: input projections gi = in @ Wih^T + bih ----------------
__global__ __launch_bounds__(384) void k_gi_enc(
    const float* __restrict__ in, const float* __restrict__ Wih,
    const float* __restrict__ bih, float* __restrict__ out, int K)
{
  __shared__ float in_s[256];
  int tb = blockIdx.x;
  for (int i = threadIdx.x; i < K; i += 384) in_s[i] = in[tb * K + i];
  __syncthreads();
  int row = threadIdx.x;
  float acc = bih[row];
  const float* wr = Wih + row * K;
  for (int k = 0; k < K; ++k) acc += in_s[k] * wr[k];
  out[tb * 384 + row] = acc;
}

// ---------------- encoder: sequential scan, one WG per direction ----------------
__global__ __launch_bounds__(512) void k_scan_enc(
    const float* __restrict__ gi_f, const float* __restrict__ gi_b,
    const float* __restrict__ whh_f, const float* __restrict__ bhh_f,
    const float* __restrict__ whh_b, const float* __restrict__ bhh_b,
    float* __restrict__ c_out)   // (32,4,256)
{
  const int dir = blockIdx.x, tid = threadIdx.x;
  const float* gi  = dir ? gi_b  : gi_f;
  const float* whh = dir ? whh_b : whh_f;
  const float* bhh = dir ? bhh_b : bhh_f;
  __shared__ unsigned short h_s[BATCH][DE + 8];
  __shared__ float gh_s[384][4];
  __shared__ float bhh_s[384];
  for (int i = tid; i < 384; i += 512) bhh_s[i] = bhh[i];
  for (int i = tid; i < BATCH * (DE + 8); i += 512) ((unsigned short*)h_s)[i] = 0;
  __syncthreads();
  for (int s = 0; s < T_M; ++s) {
    int t = dir ? (T_M - 1 - s) : s;
    #pragma unroll
    for (int k3 = 0; k3 < 3; ++k3) {
      int d = tid + 512 * k3;
      int row = d >> 2, b = d & 3;
      const float* wr = whh + row * DE;
      float acc = 0.f;
      for (int j = 0; j < DE; j += 8) {
        float4 w0 = *(const float4*)(wr + j);
        float4 w1 = *(const float4*)(wr + j + 4);
        uint4  hv = *(const uint4*)&h_s[b][j];
        acc += w0.x * blo(hv.x) + w0.y * bhi(hv.x) + w0.z * blo(hv.y) + w0.w * bhi(hv.y);
        acc += w1.x * blo(hv.z) + w1.y * bhi(hv.z) + w1.z * blo(hv.w) + w1.w * bhi(hv.w);
      }
      gh_s[row][b] = acc + bhh_s[row];
    }
    __syncthreads();
    {
      int u = tid >> 2, b = tid & 3;
      const float* git = gi + (t * BATCH + b) * 384;
      float r = sigm(git[u] + gh_s[u][b]);
      float z = sigm(git[DE + u] + gh_s[DE + u][b]);
      float n = tanhf(git[2 * DE + u] + r * gh_s[2 * DE + u][b]);
      float hold = b2f(h_s[b][u]);
      float hnew = (1.f - z) * n + z * hold;
      c_out[(t * BATCH + b) * 256 + dir * DE + u] = hnew;
      h_s[b][u] = f2b(hnew);
    }
    __syncthreads();
  }
}

// ---------------- build wav-GRU input X = [embed, upsampled c] (bf16) ----------------
__global__ __launch_bounds__(256) void k_build_X(
    const float* __restrict__ y, const float* __restrict__ E,
    const float* __restrict__ c1, unsigned short* __restrict__ X)
{
  int t = blockIdx.x, c = threadIdx.x;
  int tm = t / 80;
  #pragma unroll
  for (int b = 0; b < BATCH; ++b) {
    float w = (t == 0) ? 0.f : y[(t - 1) * BATCH + b];
    int q = (int)floorf((w + 1.f) * 128.f);
    q = q < 0 ? 0 : (q > 255 ? 255 : q);
    unsigned short* xb = X + (size_t)(t * BATCH + b) * 512;
    xb[c]       = f2b(E[q * 256 + c]);
    xb[256 + c] = f2b(c1[(tm * BATCH + b) * 256 + c]);
  }
}

// ---------------- MFMA GEMM: C(MxN) = act(A(bf16 MxK) @ B(bf16 NxK)^T + bias) -------
__global__ __launch_bounds__(256) void k_mgemm(
    const unsigned short* __restrict__ A, const unsigned short* __restrict__ B,
    const float* __restrict__ bias, void* __restrict__ C,
    int M, int N, int K, int act, int c_bf16)
{
  __shared__ unsigned short As[128][40];
  __shared__ unsigned short Bs[128][40];
  const int tid = threadIdx.x;
  const int m0 = blockIdx.x * 128, n0 = blockIdx.y * 128;
  const int lane = tid & 63, wave = tid >> 6;
  const int wy = wave >> 1, wx = wave & 1;
  const int row16 = lane & 15, quad = lane >> 4;
  const int sr = tid >> 1, sc = (tid & 1) * 16;
  f32x4 acc[4][4] = {};
  for (int kt = 0; kt < K; kt += 32) {
    uint4 av  = *(const uint4*)(A + (size_t)(m0 + sr) * K + kt + sc);
    uint4 av2 = *(const uint4*)(A + (size_t)(m0 + sr) * K + kt + sc + 8);
    uint4 bv  = *(const uint4*)(B + (size_t)(n0 + sr) * K + kt + sc);
    uint4 bv2 = *(const uint4*)(B + (size_t)(n0 + sr) * K + kt + sc + 8);
    __syncthreads();
    *(uint4*)&As[sr][sc] = av; *(uint4*)&As[sr][sc + 8] = av2;
    *(uint4*)&Bs[sr][sc] = bv; *(uint4*)&Bs[sr][sc + 8] = bv2;
    __syncthreads();
    bf16x8 af[4], bf[4];
    #pragma unroll
    for (int i = 0; i < 4; ++i) af[i] = *(const bf16x8*)&As[wy * 64 + i * 16 + row16][quad * 8];
    #pragma unroll
    for (int j = 0; j < 4; ++j) bf[j] = *(const bf16x8*)&Bs[wx * 64 + j * 16 + row16][quad * 8];
    #pragma unroll
    for (int i = 0; i < 4; ++i)
      #pragma unroll
      for (int j = 0; j < 4; ++j)
        acc[i][j] = __builtin_amdgcn_mfma_f32_16x16x32_bf16(af[i], bf[j], acc[i][j], 0, 0, 0);
  }
  #pragma unroll
  for (int i = 0; i < 4; ++i) {
    #pragma unroll
    for (int j = 0; j < 4; ++j) {
      int col = n0 + wx * 64 + j * 16 + row16;
      float bs = bias[col];
      #pragma unroll
      for (int r = 0; r < 4; ++r) {
        int row = m0 + wy * 64 + i * 16 + quad * 4 + r;
        float v = acc[i][j][r] + bs;
        if (act) v = gelu_exact(v);
        if (c_bf16) ((unsigned short*)C)[(size_t)row * N + col] = f2b(v);
        else        ((float*)C)[(size_t)row * N + col] = v;
      }
    }
  }
}

// ---------------- wav GRU: 56 persistent WGs, wave0 = sync, waves1-7 = MFMA ----------
// Packets: 2 buffers x 896 x 16B {h0h1,h2h3,tag,pad}; buf[t&1] tag==t is input h(t).
// Only wave 0 polls (no duplication); weights read as pre-swizzled L2-resident frags.
__global__ __launch_bounds__(512, 1) void k_wav_rnn(
    const unsigned short* __restrict__ whh_p,  // swizzled (NGW,3,28,4,16,8) bf16
    const float* __restrict__ bhh,             // (2688,)
    const unsigned short* __restrict__ gi,     // (10240,2688) bf16 = X@Wih^T + bih
    unsigned int* __restrict__ hslots,         // 2*896 packets of 16B, zeroed
    unsigned int* __restrict__ O32)            // (10240,448) dwords of bf16 pairs
{
  const int wg = blockIdx.x, tid = threadIdx.x;
  const int lane = tid & 63, wave = tid >> 6;

  __shared__ unsigned short h_lds[4][912];   // h(t), stride 1824B
  __shared__ float phh[7][3][4][16];         // [wave-1][gate][b][u]
  __shared__ float bhh_s[48];

  if (tid < 48) bhh_s[tid] = bhh[(tid >> 4) * 896 + wg * 16 + (tid & 15)];
  __syncthreads();

  const unsigned long long base0 = (unsigned long long)hslots;
  const unsigned long long base1 = base0 + 14336ull;

  // wave-0 registers
  float hprev = 0.f;
  float gr = 0.f, gz = 0.f, gn = 0.f;       // gi for current step
  float nr = 0.f, nz = 0.f, nn = 0.f;       // gi prefetch for next step
  const int fu = lane >> 2, fb = lane & 3;  // finalize mapping (wave 0)
  if (wave == 0) {
    const unsigned short* g0 = gi + (size_t)fb * 2688 + wg * 16 + fu;
    gr = b2f(g0[0]); gz = b2f(g0[896]); gn = b2f(g0[1792]);
  }

  // MFMA-wave constants
  const int r16 = lane & 15, quad = lane >> 4, bb = lane & 3;
  const bf16x8* W8 = (const bf16x8*)whh_p + (size_t)wg * 3 * 28 * 4 * 16;

  for (int t = 0; t < T_W; ++t) {
    if (wave == 0) {
      // ---- poll all 896 packets (14 per lane, no duplication) ----
      const unsigned long long pb = ((t & 1) ? base1 : base0) + (unsigned long long)(lane << 4);
      unsigned long long a0=pb, a1=pb+1024, a2=pb+2048, a3=pb+3072, a4=pb+4096,
        a5=pb+5120, a6=pb+6144, a7=pb+7168, a8=pb+8192, a9=pb+9216,
        a10=pb+10240, a11=pb+11264, a12=pb+12288, a13=pb+13312;
      u32x4 s0,s1,s2,s3,s4,s5,s6,s7,s8,s9,s10,s11,s12,s13;
      const unsigned int tg = (unsigned int)t;
      unsigned int bad;
      do {
        asm volatile(
          "global_load_dwordx4 %0, %14, off sc0 sc1\n"
          "global_load_dwordx4 %1, %15, off sc0 sc1\n"
          "global_load_dwordx4 %2, %16, off sc0 sc1\n"
          "global_load_dwordx4 %3, %17, off sc0 sc1\n"
          "global_load_dwordx4 %4, %18, off sc0 sc1\n"
          "global_load_dwordx4 %5, %19, off sc0 sc1\n"
          "global_load_dwordx4 %6, %20, off sc0 sc1\n"
          "global_load_dwordx4 %7, %21, off sc0 sc1\n"
          "global_load_dwordx4 %8, %22, off sc0 sc1\n"
          "global_load_dwordx4 %9, %23, off sc0 sc1\n"
          "global_load_dwordx4 %10, %24, off sc0 sc1\n"
          "global_load_dwordx4 %11, %25, off sc0 sc1\n"
          "global_load_dwordx4 %12, %26, off sc0 sc1\n"
          "global_load_dwordx4 %13, %27, off sc0 sc1\n"
          "s_waitcnt vmcnt(0)"
          : "=&v"(s0), "=&v"(s1), "=&v"(s2), "=&v"(s3), "=&v"(s4), "=&v"(s5), "=&v"(s6),
            "=&v"(s7), "=&v"(s8), "=&v"(s9), "=&v"(s10), "=&v"(s11), "=&v"(s12), "=&v"(s13)
          : "v"(a0), "v"(a1), "v"(a2), "v"(a3), "v"(a4), "v"(a5), "v"(a6),
            "v"(a7), "v"(a8), "v"(a9), "v"(a10), "v"(a11), "v"(a12), "v"(a13)
          : "memory");
        bad = (s0.z ^ tg) | (s1.z ^ tg) | (s2.z ^ tg) | (s3.z ^ tg) | (s4.z ^ tg)
            | (s5.z ^ tg) | (s6.z ^ tg) | (s7.z ^ tg) | (s8.z ^ tg) | (s9.z ^ tg)
            | (s10.z ^ tg) | (s11.z ^ tg) | (s12.z ^ tg) | (s13.z ^ tg);
      } while (__any(bad != 0));

      // ---- issue gi(t+1) prefetch (used next step; a full step of slack) ----
      if (t + 1 < T_W) {
        const unsigned short* g1 = gi + (size_t)((t + 1) * 4 + fb) * 2688 + wg * 16 + fu;
        nr = b2f(g1[0]); nz = b2f(g1[896]); nn = b2f(g1[1792]);
      }

      // ---- scatter h(t) into LDS: packet p = b*224 + G -> h_lds[b][G*4..G*4+3] ----
      #define SCAT(J, S) { int p = lane + 64 * J; int b_ = p / 224; int G_ = p - b_ * 224; \
        *(uint2*)&h_lds[b_][G_ * 4] = make_uint2(S.x, S.y); }
      SCAT(0, s0)  SCAT(1, s1)  SCAT(2, s2)  SCAT(3, s3)  SCAT(4, s4)
      SCAT(5, s5)  SCAT(6, s6)  SCAT(7, s7)  SCAT(8, s8)  SCAT(9, s9)
      SCAT(10, s10) SCAT(11, s11) SCAT(12, s12) SCAT(13, s13)
      #undef SCAT
    }
    __syncthreads();   // barrier 1: h(t) visible in LDS

    if (wave != 0) {
      const int w = wave - 1;
      f32x4 ac0 = {0.f,0.f,0.f,0.f}, ac1 = {0.f,0.f,0.f,0.f}, ac2 = {0.f,0.f,0.f,0.f};
      #pragma unroll
      for (int j = 0; j < 4; ++j) {
        const int kc = w * 4 + j;
        bf16x8 hb = *(const bf16x8*)&h_lds[bb][kc * 32 + quad * 8];
        ac0 = __builtin_amdgcn_mfma_f32_16x16x32_bf16(W8[((0 * 28 + kc) * 4 + quad) * 16 + r16], hb, ac0, 0, 0, 0);
        ac1 = __builtin_amdgcn_mfma_f32_16x16x32_bf16(W8[((1 * 28 + kc) * 4 + quad) * 16 + r16], hb, ac1, 0, 0, 0);
        ac2 = __builtin_amdgcn_mfma_f32_16x16x32_bf16(W8[((2 * 28 + kc) * 4 + quad) * 16 + r16], hb, ac2, 0, 0, 0);
      }
      if (r16 < 4) {     // D: col=lane&15 (=batch), row=quad*4+reg (=unit)
        *(f32x4*)&phh[w][0][r16][quad * 4] = ac0;
        *(f32x4*)&phh[w][1][r16][quad * 4] = ac1;
        *(f32x4*)&phh[w][2][r16][quad * 4] = ac2;
      }
    }
    __syncthreads();   // barrier 2: partial sums ready

    if (wave == 0) {
      // ---- finalize 64 h values (16 units x 4 batch) ----
      float sr = bhh_s[fu], sz = bhh_s[16 + fu], sn = bhh_s[32 + fu];
      #pragma unroll
      for (int w = 0; w < 7; ++w) {
        sr += phh[w][0][fb][fu];
        sz += phh[w][1][fb][fu];
        sn += phh[w][2][fb][fu];
      }
      float r = sigm(gr + sr);
      float z = sigm(gz + sz);
      float n = tanhf(gn + r * sn);
      float hnew = (1.f - z) * n + z * hprev;
      hprev = hnew;
      unsigned int hu = f2b(hnew);
      gr = nr; gz = nz; gn = nn;

      // ---- publish: lanes 0..15 own packet (q=lane>>2, b=lane&3) ----
      int q = lane >> 2, pbt = lane & 3;
      unsigned int v0 = (unsigned int)__shfl((int)hu, (q * 4 + 0) * 4 + pbt);
      unsigned int v1 = (unsigned int)__shfl((int)hu, (q * 4 + 1) * 4 + pbt);
      unsigned int v2 = (unsigned int)__shfl((int)hu, (q * 4 + 2) * 4 + pbt);
      unsigned int v3 = (unsigned int)__shfl((int)hu, (q * 4 + 3) * 4 + pbt);
      if (lane < 16) {
        u32x4 pkt;
        pkt.x = (v0 & 0xffffu) | (v1 << 16);
        pkt.y = (v2 & 0xffffu) | (v3 << 16);
        pkt.z = (unsigned int)(t + 1);
        pkt.w = 0u;
        *(uint2*)(O32 + (size_t)(t * 4 + pbt) * 448 + wg * 8 + q * 2) = make_uint2(pkt.x, pkt.y);
        unsigned long long sa = (((t + 1) & 1) ? base1 : base0)
                              + (unsigned long long)((pbt * 224 + wg * 4 + q) << 4);
        asm volatile("global_store_dwordx4 %0, %1, off sc0 sc1"
                     :: "v"(sa), "v"(pkt) : "memory");
      }
    }
  }
}

// ---------------- NLL ----------------
__global__ __launch_bounds__(256) void k_nll(
    const float* __restrict__ logits, const float* __restrict__ y,
    float* __restrict__ acc)
{
  int wid = threadIdx.x >> 6, lane = threadIdx.x & 63;
  int row = blockIdx.x * 4 + wid;
  const float* lr = logits + (size_t)row * 256;
  float v0 = lr[lane], v1 = lr[lane + 64], v2 = lr[lane + 128], v3 = lr[lane + 192];
  float mx = fmaxf(fmaxf(v0, v1), fmaxf(v2, v3));
  for (int off = 32; off > 0; off >>= 1) mx = fmaxf(mx, __shfl_xor(mx, off));
  float se = __expf(v0 - mx) + __expf(v1 - mx) + __expf(v2 - mx) + __expf(v3 - mx);
  for (int off = 32; off > 0; off >>= 1) se += __shfl_xor(se, off);
  if (lane == 0) {
    float w = y[row];
    int q = (int)floorf((w + 1.f) * 128.f);
    q = q < 0 ? 0 : (q > 255 ? 255 : q);
    float contrib = (logf(se) + mx) - lr[q];
    atomicAdd(acc, contrib);
  }
}

__global__ void k_final(const float* __restrict__ acc, float* __restrict__ out) {
  out[0] = acc[0] * (1.f / 10240.f);
}

// ---------------- host ----------------
extern "C" void kernel_launch(void* const* d_in, const int* in_sizes, int n_in,
                              void* d_out, int out_size, void* d_ws, size_t ws_size,
                              hipStream_t stream)
{
  const float* x       = (const float*)d_in[0];
  const float* y       = (const float*)d_in[1];
  const float* m0f_Wih = (const float*)d_in[2];
  const float* m0f_Whh = (const float*)d_in[3];
  const float* m0f_bih = (const float*)d_in[4];
  const float* m0f_bhh = (const float*)d_in[5];
  const float* m0b_Wih = (const float*)d_in[6];
  const float* m0b_Whh = (const float*)d_in[7];
  const float* m0b_bih = (const float*)d_in[8];
  const float* m0b_bhh = (const float*)d_in[9];
  const float* m1f_Wih = (const float*)d_in[10];
  const float* m1f_Whh = (const float*)d_in[11];
  const float* m1f_bih = (const float*)d_in[12];
  const float* m1f_bhh = (const float*)d_in[13];
  const float* m1b_Wih = (const float*)d_in[14];
  const float* m1b_Whh = (const float*)d_in[15];
  const float* m1b_bih = (const float*)d_in[16];
  const float* m1b_bhh = (const float*)d_in[17];
  const float* w_Wih   = (const float*)d_in[18];
  const float* w_Whh   = (const float*)d_in[19];
  const float* w_bih   = (const float*)d_in[20];
  const float* w_bhh   = (const float*)d_in[21];
  const float* Wp      = (const float*)d_in[22];
  const float* bp      = (const float*)d_in[23];
  const float* E       = (const float*)d_in[24];
  const float* Wd      = (const float*)d_in[25];
  const float* bd      = (const float*)d_in[26];

  char* ws = (char*)d_ws;
  size_t off = 0;
  auto alloc = [&](size_t bytes) -> void* {
    void* p = ws + off;
    off += (bytes + 255) & ~(size_t)255;
    return p;
  };
  // misc (zeroed each launch): nll acc + h packet buffers
  float*        nacc   = (float*)alloc(64);
  unsigned int* hslots = (unsigned int*)alloc(2 * 896 * 16);
  size_t misc_bytes = off;

  float* c0   = (float*)alloc((size_t)32 * 4 * 256 * 4);
  float* c1   = (float*)alloc((size_t)32 * 4 * 256 * 4);
  float* gi0f = (float*)alloc((size_t)32 * 4 * 384 * 4);
  float* gi0b = (float*)alloc((size_t)32 * 4 * 384 * 4);
  float* gi1f = (float*)alloc((size_t)32 * 4 * 384 * 4);
  float* gi1b = (float*)alloc((size_t)32 * 4 * 384 * 4);
  unsigned short* X     = (unsigned short*)alloc((size_t)10240 * 512 * 2);
  unsigned short* gi_w  = (unsigned short*)alloc((size_t)10240 * 2688 * 2);
  unsigned int*   O32   = (unsigned int*)alloc((size_t)10240 * 448 * 4);
  unsigned short* O2    = (unsigned short*)alloc((size_t)10240 * 512 * 2);
  float*          LG    = (float*)alloc((size_t)10240 * 256 * 4);
  unsigned short* Wih_b = (unsigned short*)alloc((size_t)2688 * 512 * 2);
  unsigned short* Whh_p = (unsigned short*)alloc((size_t)2688 * 896 * 2);
  unsigned short* Wp_b  = (unsigned short*)alloc((size_t)512 * 896 * 2);
  unsigned short* Wd_b  = (unsigned short*)alloc((size_t)256 * 512 * 2);

  hipMemsetAsync(d_ws, 0, misc_bytes, stream);

  // weight preprocessing
  k_cast<<<(2688 * 512 + 255) / 256, 256, 0, stream>>>(w_Wih, Wih_b, 2688 * 512);
  k_cast<<<(512 * 896 + 255) / 256, 256, 0, stream>>>(Wp, Wp_b, 512 * 896);
  k_cast<<<(256 * 512 + 255) / 256, 256, 0, stream>>>(Wd, Wd_b, 256 * 512);
  k_prep_whh<<<(2688 * 896 + 255) / 256, 256, 0, stream>>>(w_Whh, Whh_p);

  // encoder
  k_gi_enc<<<128, 384, 0, stream>>>(x, m0f_Wih, m0f_bih, gi0f, 80);
  k_gi_enc<<<128, 384, 0, stream>>>(x, m0b_Wih, m0b_bih, gi0b, 80);
  k_scan_enc<<<2, 512, 0, stream>>>(gi0f, gi0b, m0f_Whh, m0f_bhh, m0b_Whh, m0b_bhh, c0);
  k_gi_enc<<<128, 384, 0, stream>>>(c0, m1f_Wih, m1f_bih, gi1f, 256);
  k_gi_enc<<<128, 384, 0, stream>>>(c0, m1b_Wih, m1b_bih, gi1b, 256);
  k_scan_enc<<<2, 512, 0, stream>>>(gi1f, gi1b, m1f_Whh, m1f_bhh, m1b_Whh, m1b_bhh, c1);

  // wav input + precomputed input projection (includes bih)
  k_build_X<<<2560, 256, 0, stream>>>(y, E, c1, X);
  k_mgemm<<<dim3(80, 21), 256, 0, stream>>>(X, Wih_b, w_bih, (void*)gi_w,
                                            10240, 2688, 512, 0, 1);

  // recurrent wav GRU (persistent, tag-based sync; 56 WGs all resident)
  k_wav_rnn<<<NGW, 512, 0, stream>>>(Whh_p, w_bhh, gi_w, hslots, O32);

  // head
  k_mgemm<<<dim3(80, 4), 256, 0, stream>>>((const unsigned short*)O32, Wp_b, bp,
                                           (void*)O2, 10240, 512, 896, 1, 1);
  k_mgemm<<<dim3(80, 2), 256, 0, stream>>>(O2, Wd_b, bd, (void*)LG,
                                           10240, 256, 512, 0, 0);
  k_nll<<<2560, 256, 0, stream>>>(LG, y, nacc);
  k_final<<<1, 1, 0, stream>>>(nacc, (float*)d_out);
}

// Round 6
// 6150.613 us; speedup vs baseline: 2.0979x; 1.4404x over previous
//
#include <hip/hip_runtime.h>
#include <stdint.h>
#include <math.h>

typedef __attribute__((ext_vector_type(8))) short bf16x8;
typedef __attribute__((ext_vector_type(4))) float f32x4;
typedef __attribute__((ext_vector_type(4))) unsigned int u32x4;

#define BATCH 4
#define T_M 32
#define DE 128
#define T_W 2560
#define NWG 28        /* wav-rnn WGs; 8 waves each; wave owns 4 units; 28*8*4 = 896 */

__device__ __forceinline__ float b2f(unsigned short h) {
  return __uint_as_float(((unsigned int)h) << 16);
}
__device__ __forceinline__ unsigned short f2b(float f) {
  unsigned int u = __float_as_uint(f);
  u = u + 0x7fffu + ((u >> 16) & 1u);   // RNE
  return (unsigned short)(u >> 16);
}
__device__ __forceinline__ float blo(unsigned int u){ return __uint_as_float(u << 16); }
__device__ __forceinline__ float bhi(unsigned int u){ return __uint_as_float(u & 0xffff0000u); }
__device__ __forceinline__ float sigm(float x){ return 1.f / (1.f + __expf(-x)); }
__device__ __forceinline__ float gelu_exact(float x){ return 0.5f * x * (1.f + erff(x * 0.70710678118654752f)); }

// ---------------- fp32 -> bf16 cast ----------------
__global__ __launch_bounds__(256) void k_cast(const float* __restrict__ src,
                                              unsigned short* __restrict__ dst, int n)
{
  int i = blockIdx.x * 256 + threadIdx.x;
  if (i < n) dst[i] = f2b(src[i]);
}

// ---------------- pre-swizzle Whh into per-(G,kc) MFMA A-fragments ----------------
// G = wg*8 + wave (224 groups of 4 units). Fragment element:
// out[(((G*28+kc)*4+quad)*16 + r16)*8 + j] ; r16<12: row=(r16>>2)*896 + G*4 + (r16&3),
// col = kc*32 + quad*8 + j ; rows 12..15 zero.
__global__ __launch_bounds__(256) void k_prep_whh(const float* __restrict__ whh,
                                                  unsigned short* __restrict__ out)
{
  int idx = blockIdx.x * 256 + threadIdx.x;
  if (idx >= 224 * 28 * 512) return;
  int j    = idx & 7;
  int r16  = (idx >> 3) & 15;
  int quad = (idx >> 7) & 3;
  int kc   = (idx >> 9) % 28;
  int G    = (idx >> 9) / 28;
  unsigned short val = 0;
  if (r16 < 12) {
    int row = (r16 >> 2) * 896 + G * 4 + (r16 & 3);
    int col = kc * 32 + quad * 8 + j;
    val = f2b(whh[(size_t)row * 896 + col]);
  }
  out[idx] = val;
}

// ---------------- encoder: input projections gi = in @ Wih^T + bih ----------------
__global__ __launch_bounds__(384) void k_gi_enc(
    const float* __restrict__ in, const float* __restrict__ Wih,
    const float* __restrict__ bih, float* __restrict__ out, int K)
{
  __shared__ float in_s[256];
  int tb = blockIdx.x;
  for (int i = threadIdx.x; i < K; i += 384) in_s[i] = in[tb * K + i];
  __syncthreads();
  int row = threadIdx.x;
  float acc = bih[row];
  const float* wr = Wih + row * K;
  for (int k = 0; k < K; ++k) acc += in_s[k] * wr[k];
  out[tb * 384 + row] = acc;
}

// ---------------- encoder: sequential scan, one WG per direction ----------------
__global__ __launch_bounds__(512) void k_scan_enc(
    const float* __restrict__ gi_f, const float* __restrict__ gi_b,
    const float* __restrict__ whh_f, const float* __restrict__ bhh_f,
    const float* __restrict__ whh_b, const float* __restrict__ bhh_b,
    float* __restrict__ c_out)   // (32,4,256)
{
  const int dir = blockIdx.x, tid = threadIdx.x;
  const float* gi  = dir ? gi_b  : gi_f;
  const float* whh = dir ? whh_b : whh_f;
  const float* bhh = dir ? bhh_b : bhh_f;
  __shared__ unsigned short h_s[BATCH][DE + 8];
  __shared__ float gh_s[384][4];
  __shared__ float bhh_s[384];
  for (int i = tid; i < 384; i += 512) bhh_s[i] = bhh[i];
  for (int i = tid; i < BATCH * (DE + 8); i += 512) ((unsigned short*)h_s)[i] = 0;
  __syncthreads();
  for (int s = 0; s < T_M; ++s) {
    int t = dir ? (T_M - 1 - s) : s;
    #pragma unroll
    for (int k3 = 0; k3 < 3; ++k3) {
      int d = tid + 512 * k3;
      int row = d >> 2, b = d & 3;
      const float* wr = whh + row * DE;
      float acc = 0.f;
      for (int j = 0; j < DE; j += 8) {
        float4 w0 = *(const float4*)(wr + j);
        float4 w1 = *(const float4*)(wr + j + 4);
        uint4  hv = *(const uint4*)&h_s[b][j];
        acc += w0.x * blo(hv.x) + w0.y * bhi(hv.x) + w0.z * blo(hv.y) + w0.w * bhi(hv.y);
        acc += w1.x * blo(hv.z) + w1.y * bhi(hv.z) + w1.z * blo(hv.w) + w1.w * bhi(hv.w);
      }
      gh_s[row][b] = acc + bhh_s[row];
    }
    __syncthreads();
    {
      int u = tid >> 2, b = tid & 3;
      const float* git = gi + (t * BATCH + b) * 384;
      float r = sigm(git[u] + gh_s[u][b]);
      float z = sigm(git[DE + u] + gh_s[DE + u][b]);
      float n = tanhf(git[2 * DE + u] + r * gh_s[2 * DE + u][b]);
      float hold = b2f(h_s[b][u]);
      float hnew = (1.f - z) * n + z * hold;
      c_out[(t * BATCH + b) * 256 + dir * DE + u] = hnew;
      h_s[b][u] = f2b(hnew);
    }
    __syncthreads();
  }
}

// ---------------- build wav-GRU input X = [embed, upsampled c] (bf16) ----------------
__global__ __launch_bounds__(256) void k_build_X(
    const float* __restrict__ y, const float* __restrict__ E,
    const float* __restrict__ c1, unsigned short* __restrict__ X)
{
  int t = blockIdx.x, c = threadIdx.x;
  int tm = t / 80;
  #pragma unroll
  for (int b = 0; b < BATCH; ++b) {
    float w = (t == 0) ? 0.f : y[(t - 1) * BATCH + b];
    int q = (int)floorf((w + 1.f) * 128.f);
    q = q < 0 ? 0 : (q > 255 ? 255 : q);
    unsigned short* xb = X + (size_t)(t * BATCH + b) * 512;
    xb[c]       = f2b(E[q * 256 + c]);
    xb[256 + c] = f2b(c1[(tm * BATCH + b) * 256 + c]);
  }
}

// ---------------- MFMA GEMM: C(MxN) = act(A(bf16 MxK) @ B(bf16 NxK)^T + bias) -------
__global__ __launch_bounds__(256) void k_mgemm(
    const unsigned short* __restrict__ A, const unsigned short* __restrict__ B,
    const float* __restrict__ bias, void* __restrict__ C,
    int M, int N, int K, int act, int c_bf16)
{
  __shared__ unsigned short As[128][40];
  __shared__ unsigned short Bs[128][40];
  const int tid = threadIdx.x;
  const int m0 = blockIdx.x * 128, n0 = blockIdx.y * 128;
  const int lane = tid & 63, wave = tid >> 6;
  const int wy = wave >> 1, wx = wave & 1;
  const int row16 = lane & 15, quad = lane >> 4;
  const int sr = tid >> 1, sc = (tid & 1) * 16;
  f32x4 acc[4][4] = {};
  for (int kt = 0; kt < K; kt += 32) {
    uint4 av  = *(const uint4*)(A + (size_t)(m0 + sr) * K + kt + sc);
    uint4 av2 = *(const uint4*)(A + (size_t)(m0 + sr) * K + kt + sc + 8);
    uint4 bv  = *(const uint4*)(B + (size_t)(n0 + sr) * K + kt + sc);
    uint4 bv2 = *(const uint4*)(B + (size_t)(n0 + sr) * K + kt + sc + 8);
    __syncthreads();
    *(uint4*)&As[sr][sc] = av; *(uint4*)&As[sr][sc + 8] = av2;
    *(uint4*)&Bs[sr][sc] = bv; *(uint4*)&Bs[sr][sc + 8] = bv2;
    __syncthreads();
    bf16x8 af[4], bf[4];
    #pragma unroll
    for (int i = 0; i < 4; ++i) af[i] = *(const bf16x8*)&As[wy * 64 + i * 16 + row16][quad * 8];
    #pragma unroll
    for (int j = 0; j < 4; ++j) bf[j] = *(const bf16x8*)&Bs[wx * 64 + j * 16 + row16][quad * 8];
    #pragma unroll
    for (int i = 0; i < 4; ++i)
      #pragma unroll
      for (int j = 0; j < 4; ++j)
        acc[i][j] = __builtin_amdgcn_mfma_f32_16x16x32_bf16(af[i], bf[j], acc[i][j], 0, 0, 0);
  }
  #pragma unroll
  for (int i = 0; i < 4; ++i) {
    #pragma unroll
    for (int j = 0; j < 4; ++j) {
      int col = n0 + wx * 64 + j * 16 + row16;
      float bs = bias[col];
      #pragma unroll
      for (int r = 0; r < 4; ++r) {
        int row = m0 + wy * 64 + i * 16 + quad * 4 + r;
        float v = acc[i][j][r] + bs;
        if (act) v = gelu_exact(v);
        if (c_bf16) ((unsigned short*)C)[(size_t)row * N + col] = f2b(v);
        else        ((float*)C)[(size_t)row * N + col] = v;
      }
    }
  }
}

// ---------------- wav GRU: 28 WGs x 8 waves; every wave polls/computes/publishes -----
// Proven LLC protocol (sc0 sc1 packet stores/loads, tag-in-16B-packet, double buffer).
// Wave owns 4 h-units: 28 MFMAs from 112 VGPRs of pre-swizzled Whh; in-wave finalize.
__global__ __launch_bounds__(512, 1) void k_wav_rnn(
    const unsigned short* __restrict__ whh_p,  // swizzled (224,28,4,16,8) bf16
    const float* __restrict__ bhh,             // (2688,)
    const unsigned short* __restrict__ gi,     // (10240,2688) bf16 = X@Wih^T + bih
    unsigned int* __restrict__ hslots,         // 2*896 packets of 16B, zeroed
    unsigned int* __restrict__ O32)            // (10240,448) dwords of bf16 pairs
{
  const int wg = blockIdx.x, tid = threadIdx.x;
  const int lane = tid & 63, wave = tid >> 6;
  const int G = wg * 8 + wave;                 // global 4-unit group

  __shared__ unsigned short h_lds[4][912];     // h(t), stride 1824B
  __shared__ float phh[8][3][4][4];            // [wave][gate][batch][unit]

  const int r16 = lane & 15, quad = lane >> 4, bb = lane & 3;
  const int fu = (lane >> 2) & 3, fb = lane & 3;   // finalize mapping (lanes 0-15 real)

  // ---- Whh fragments -> VGPRs (28 x bf16x8 = 112 VGPRs), coalesced 16B/lane ----
  bf16x8 wf[28];
  {
    const bf16x8* W8 = (const bf16x8*)whh_p + (size_t)G * 28 * 64;
    #pragma unroll
    for (int kc = 0; kc < 28; ++kc)
      wf[kc] = W8[(kc * 4 + quad) * 16 + r16];
  }

  // ---- per-lane bias + recurrent state ----
  const float br_ = bhh[G * 4 + fu];
  const float bz_ = bhh[896 + G * 4 + fu];
  const float bn_ = bhh[1792 + G * 4 + fu];
  float hprev = 0.f;
  const unsigned short* gbase = gi + G * 4 + fu;
  unsigned short cr = gbase[(size_t)fb * 2688];          // gi(0), raw bf16 bits
  unsigned short cz = gbase[(size_t)fb * 2688 + 896];
  unsigned short cn = gbase[(size_t)fb * 2688 + 1792];

  // ---- poll slice: wave covers packets [wave*112, wave*112+112) ----
  const int l56 = (lane < 56) ? lane : (lane - 56);
  const int p0 = wave * 112 + l56;
  const int p1 = p0 + 56;
  const int pb0 = p0 / 224, pG0 = p0 - pb0 * 224;
  const int pb1 = p1 / 224, pG1 = p1 - pb1 * 224;

  const unsigned long long base0 = (unsigned long long)hslots;
  const unsigned long long base1 = base0 + 14336ull;

  for (int t = 0; t < T_W; ++t) {
    // ---- poll my 2 packets (tags == t) ----
    const unsigned long long hb = (t & 1) ? base1 : base0;
    unsigned long long a0 = hb + ((unsigned long long)p0 << 4);
    unsigned long long a1 = hb + ((unsigned long long)p1 << 4);
    u32x4 s0, s1;
    const unsigned int tg = (unsigned int)t;
    unsigned int bad;
    do {
      asm volatile(
        "global_load_dwordx4 %0, %2, off sc0 sc1\n"
        "global_load_dwordx4 %1, %3, off sc0 sc1\n"
        "s_waitcnt vmcnt(0)"
        : "=&v"(s0), "=&v"(s1)
        : "v"(a0), "v"(a1)
        : "memory");
      bad = (s0.z ^ tg) | (s1.z ^ tg);
    } while (__any(bad != 0));

    // ---- scatter h(t) into LDS (lanes < 56; 112 packets per wave) ----
    if (lane < 56) {
      *(uint2*)&h_lds[pb0][pG0 * 4] = make_uint2(s0.x, s0.y);
      *(uint2*)&h_lds[pb1][pG1 * 4] = make_uint2(s1.x, s1.y);
    }
    __syncthreads();   // barrier A: h(t) fully in LDS

    // ---- issue gi(t+1) loads (raw ushort; consumed at end of step) ----
    int tn = (t + 1 < T_W) ? (t + 1) : t;
    const unsigned short* gp = gbase + (size_t)(tn * 4 + fb) * 2688;
    unsigned short nr_ = gp[0], nz_ = gp[896], nn_ = gp[1792];

    // ---- 28 MFMAs, 4 interleaved accumulator chains ----
    f32x4 ac0 = {}, ac1 = {}, ac2 = {}, ac3 = {};
    #pragma unroll
    for (int kc = 0; kc < 28; kc += 4) {
      bf16x8 h0 = *(const bf16x8*)&h_lds[bb][(kc + 0) * 32 + quad * 8];
      bf16x8 h1 = *(const bf16x8*)&h_lds[bb][(kc + 1) * 32 + quad * 8];
      bf16x8 h2 = *(const bf16x8*)&h_lds[bb][(kc + 2) * 32 + quad * 8];
      bf16x8 h3 = *(const bf16x8*)&h_lds[bb][(kc + 3) * 32 + quad * 8];
      ac0 = __builtin_amdgcn_mfma_f32_16x16x32_bf16(wf[kc + 0], h0, ac0, 0, 0, 0);
      ac1 = __builtin_amdgcn_mfma_f32_16x16x32_bf16(wf[kc + 1], h1, ac1, 0, 0, 0);
      ac2 = __builtin_amdgcn_mfma_f32_16x16x32_bf16(wf[kc + 2], h2, ac2, 0, 0, 0);
      ac3 = __builtin_amdgcn_mfma_f32_16x16x32_bf16(wf[kc + 3], h3, ac3, 0, 0, 0);
    }
    f32x4 ac;
    ac[0] = ac0[0] + ac1[0] + ac2[0] + ac3[0];
    ac[1] = ac0[1] + ac1[1] + ac2[1] + ac3[1];
    ac[2] = ac0[2] + ac1[2] + ac2[2] + ac3[2];
    ac[3] = ac0[3] + ac1[3] + ac2[3] + ac3[3];

    // ---- in-wave transpose via LDS: D[row=quad*4+reg][col=r16] -> phh[v][g][b][u] ----
    if (r16 < 4 && quad < 3)
      *(f32x4*)&phh[wave][quad][r16][0] = ac;
    asm volatile("s_waitcnt lgkmcnt(0)" ::: "memory");   // same-wave DS in-order

    // ---- finalize my 16 h values (lanes 0-15; others duplicate harmlessly) ----
    float pr = phh[wave][0][fb][fu];
    float pz = phh[wave][1][fb][fu];
    float pn = phh[wave][2][fb][fu];
    float r = sigm(b2f(cr) + br_ + pr);
    float z = sigm(b2f(cz) + bz_ + pz);
    float n = tanhf(b2f(cn) + bn_ + r * pn);
    float h = (1.f - z) * n + z * hprev;
    hprev = h;
    unsigned int hu = f2b(h);
    cr = nr_; cz = nz_; cn = nn_;

    // ---- publish: lanes 0-3 own packet (batch b = lane) ----
    int b = lane & 3;
    unsigned int u0v = (unsigned int)__shfl((int)hu, 0 + b);
    unsigned int u1v = (unsigned int)__shfl((int)hu, 4 + b);
    unsigned int u2v = (unsigned int)__shfl((int)hu, 8 + b);
    unsigned int u3v = (unsigned int)__shfl((int)hu, 12 + b);
    if (lane < 4) {
      u32x4 pkt;
      pkt.x = (u0v & 0xffffu) | (u1v << 16);
      pkt.y = (u2v & 0xffffu) | (u3v << 16);
      pkt.z = (unsigned int)(t + 1);
      pkt.w = 0u;
      *(uint2*)(O32 + (size_t)(t * 4 + b) * 448 + G * 2) = make_uint2(pkt.x, pkt.y);
      unsigned long long sa = (((t + 1) & 1) ? base1 : base0)
                            + (unsigned long long)((b * 224 + G) << 4);
      asm volatile("global_store_dwordx4 %0, %1, off sc0 sc1"
                   :: "v"(sa), "v"(pkt) : "memory");
    }
    __syncthreads();   // barrier B: all local reads of h_lds(t) done before next scatter
  }
}

// ---------------- NLL ----------------
__global__ __launch_bounds__(256) void k_nll(
    const float* __restrict__ logits, const float* __restrict__ y,
    float* __restrict__ acc)
{
  int wid = threadIdx.x >> 6, lane = threadIdx.x & 63;
  int row = blockIdx.x * 4 + wid;
  const float* lr = logits + (size_t)row * 256;
  float v0 = lr[lane], v1 = lr[lane + 64], v2 = lr[lane + 128], v3 = lr[lane + 192];
  float mx = fmaxf(fmaxf(v0, v1), fmaxf(v2, v3));
  for (int off = 32; off > 0; off >>= 1) mx = fmaxf(mx, __shfl_xor(mx, off));
  float se = __expf(v0 - mx) + __expf(v1 - mx) + __expf(v2 - mx) + __expf(v3 - mx);
  for (int off = 32; off > 0; off >>= 1) se += __shfl_xor(se, off);
  if (lane == 0) {
    float w = y[row];
    int q = (int)floorf((w + 1.f) * 128.f);
    q = q < 0 ? 0 : (q > 255 ? 255 : q);
    float contrib = (logf(se) + mx) - lr[q];
    atomicAdd(acc, contrib);
  }
}

__global__ void k_final(const float* __restrict__ acc, float* __restrict__ out) {
  out[0] = acc[0] * (1.f / 10240.f);
}

// ---------------- host ----------------
extern "C" void kernel_launch(void* const* d_in, const int* in_sizes, int n_in,
                              void* d_out, int out_size, void* d_ws, size_t ws_size,
                              hipStream_t stream)
{
  const float* x       = (const float*)d_in[0];
  const float* y       = (const float*)d_in[1];
  const float* m0f_Wih = (const float*)d_in[2];
  const float* m0f_Whh = (const float*)d_in[3];
  const float* m0f_bih = (const float*)d_in[4];
  const float* m0f_bhh = (const float*)d_in[5];
  const float* m0b_Wih = (const float*)d_in[6];
  const float* m0b_Whh = (const float*)d_in[7];
  const float* m0b_bih = (const float*)d_in[8];
  const float* m0b_bhh = (const float*)d_in[9];
  const float* m1f_Wih = (const float*)d_in[10];
  const float* m1f_Whh = (const float*)d_in[11];
  const float* m1f_bih = (const float*)d_in[12];
  const float* m1f_bhh = (const float*)d_in[13];
  const float* m1b_Wih = (const float*)d_in[14];
  const float* m1b_Whh = (const float*)d_in[15];
  const float* m1b_bih = (const float*)d_in[16];
  const float* m1b_bhh = (const float*)d_in[17];
  const float* w_Wih   = (const float*)d_in[18];
  const float* w_Whh   = (const float*)d_in[19];
  const float* w_bih   = (const float*)d_in[20];
  const float* w_bhh   = (const float*)d_in[21];
  const float* Wp      = (const float*)d_in[22];
  const float* bp      = (const float*)d_in[23];
  const float* E       = (const float*)d_in[24];
  const float* Wd      = (const float*)d_in[25];
  const float* bd      = (const float*)d_in[26];

  char* ws = (char*)d_ws;
  size_t off = 0;
  auto alloc = [&](size_t bytes) -> void* {
    void* p = ws + off;
    off += (bytes + 255) & ~(size_t)255;
    return p;
  };
  // misc (zeroed each launch): nll acc + h packet buffers
  float*        nacc   = (float*)alloc(64);
  unsigned int* hslots = (unsigned int*)alloc(2 * 896 * 16);
  size_t misc_bytes = off;

  float* c0   = (float*)alloc((size_t)32 * 4 * 256 * 4);
  float* c1   = (float*)alloc((size_t)32 * 4 * 256 * 4);
  float* gi0f = (float*)alloc((size_t)32 * 4 * 384 * 4);
  float* gi0b = (float*)alloc((size_t)32 * 4 * 384 * 4);
  float* gi1f = (float*)alloc((size_t)32 * 4 * 384 * 4);
  float* gi1b = (float*)alloc((size_t)32 * 4 * 384 * 4);
  unsigned short* X     = (unsigned short*)alloc((size_t)10240 * 512 * 2);
  unsigned short* gi_w  = (unsigned short*)alloc((size_t)10240 * 2688 * 2);
  unsigned int*   O32   = (unsigned int*)alloc((size_t)10240 * 448 * 4);
  unsigned short* O2    = (unsigned short*)alloc((size_t)10240 * 512 * 2);
  float*          LG    = (float*)alloc((size_t)10240 * 256 * 4);
  unsigned short* Wih_b = (unsigned short*)alloc((size_t)2688 * 512 * 2);
  unsigned short* Whh_p = (unsigned short*)alloc((size_t)224 * 28 * 512 * 2);
  unsigned short* Wp_b  = (unsigned short*)alloc((size_t)512 * 896 * 2);
  unsigned short* Wd_b  = (unsigned short*)alloc((size_t)256 * 512 * 2);

  hipMemsetAsync(d_ws, 0, misc_bytes, stream);

  // weight preprocessing
  k_cast<<<(2688 * 512 + 255) / 256, 256, 0, stream>>>(w_Wih, Wih_b, 2688 * 512);
  k_cast<<<(512 * 896 + 255) / 256, 256, 0, stream>>>(Wp, Wp_b, 512 * 896);
  k_cast<<<(256 * 512 + 255) / 256, 256, 0, stream>>>(Wd, Wd_b, 256 * 512);
  k_prep_whh<<<(224 * 28 * 512 + 255) / 256, 256, 0, stream>>>(w_Whh, Whh_p);

  // encoder
  k_gi_enc<<<128, 384, 0, stream>>>(x, m0f_Wih, m0f_bih, gi0f, 80);
  k_gi_enc<<<128, 384, 0, stream>>>(x, m0b_Wih, m0b_bih, gi0b, 80);
  k_scan_enc<<<2, 512, 0, stream>>>(gi0f, gi0b, m0f_Whh, m0f_bhh, m0b_Whh, m0b_bhh, c0);
  k_gi_enc<<<128, 384, 0, stream>>>(c0, m1f_Wih, m1f_bih, gi1f, 256);
  k_gi_enc<<<128, 384, 0, stream>>>(c0, m1b_Wih, m1b_bih, gi1b, 256);
  k_scan_enc<<<2, 512, 0, stream>>>(gi1f, gi1b, m1f_Whh, m1f_bhh, m1b_Whh, m1b_bhh, c1);

  // wav input + precomputed input projection (includes bih)
  k_build_X<<<2560, 256, 0, stream>>>(y, E, c1, X);
  k_mgemm<<<dim3(80, 21), 256, 0, stream>>>(X, Wih_b, w_bih, (void*)gi_w,
                                            10240, 2688, 512, 0, 1);

  // recurrent wav GRU (persistent, tag-based LLC sync; 28 WGs, 8 waves each)
  k_wav_rnn<<<NWG, 512, 0, stream>>>(Whh_p, w_bhh, gi_w, hslots, O32);

  // head
  k_mgemm<<<dim3(80, 4), 256, 0, stream>>>((const unsigned short*)O32, Wp_b, bp,
                                           (void*)O2, 10240, 512, 896, 1, 1);
  k_mgemm<<<dim3(80, 2), 256, 0, stream>>>(O2, Wd_b, bd, (void*)LG,
                                           10240, 256, 512, 0, 0);
  k_nll<<<2560, 256, 0, stream>>>(LG, y, nacc);
  k_final<<<1, 1, 0, stream>>>(nacc, (float*)d_out);
}

// Round 7
// 5992.024 us; speedup vs baseline: 2.1535x; 1.0265x over previous
//
#include <hip/hip_runtime.h>
#include <stdint.h>
#include <math.h>

typedef __attribute__((ext_vector_type(8))) short bf16x8;
typedef __attribute__((ext_vector_type(4))) float f32x4;
typedef __attribute__((ext_vector_type(4))) unsigned int u32x4;

#define BATCH 4
#define T_M 32
#define DE 128
#define T_W 2560
#define NWG 28        /* wav-rnn WGs; 8 waves each; wave owns 4 units; 28*8*4 = 896 */

__device__ __forceinline__ float b2f(unsigned short h) {
  return __uint_as_float(((unsigned int)h) << 16);
}
__device__ __forceinline__ unsigned short f2b(float f) {
  unsigned int u = __float_as_uint(f);
  u = u + 0x7fffu + ((u >> 16) & 1u);   // RNE
  return (unsigned short)(u >> 16);
}
__device__ __forceinline__ float blo(unsigned int u){ return __uint_as_float(u << 16); }
__device__ __forceinline__ float bhi(unsigned int u){ return __uint_as_float(u & 0xffff0000u); }
__device__ __forceinline__ float sigm(float x){
  return __builtin_amdgcn_rcpf(1.f + __expf(-x));
}
__device__ __forceinline__ float tanh_fast(float x){
  float x2 = fminf(fmaxf(x + x, -30.f), 30.f);
  return 1.f - 2.f * __builtin_amdgcn_rcpf(__expf(x2) + 1.f);
}
__device__ __forceinline__ float gelu_exact(float x){ return 0.5f * x * (1.f + erff(x * 0.70710678118654752f)); }

// ---------------- fp32 -> bf16 cast ----------------
__global__ __launch_bounds__(256) void k_cast(const float* __restrict__ src,
                                              unsigned short* __restrict__ dst, int n)
{
  int i = blockIdx.x * 256 + threadIdx.x;
  if (i < n) dst[i] = f2b(src[i]);
}

// ---------------- pre-swizzle Whh into per-(G,kc) MFMA A-fragments ----------------
// G = wg*8 + wave (224 groups of 4 units). Fragment element:
// out[(((G*28+kc)*4+quad)*16 + r16)*8 + j] ; r16<12: row=(r16>>2)*896 + G*4 + (r16&3),
// col = kc*32 + quad*8 + j ; rows 12..15 zero.
__global__ __launch_bounds__(256) void k_prep_whh(const float* __restrict__ whh,
                                                  unsigned short* __restrict__ out)
{
  int idx = blockIdx.x * 256 + threadIdx.x;
  if (idx >= 224 * 28 * 512) return;
  int j    = idx & 7;
  int r16  = (idx >> 3) & 15;
  int quad = (idx >> 7) & 3;
  int kc   = (idx >> 9) % 28;
  int G    = (idx >> 9) / 28;
  unsigned short val = 0;
  if (r16 < 12) {
    int row = (r16 >> 2) * 896 + G * 4 + (r16 & 3);
    int col = kc * 32 + quad * 8 + j;
    val = f2b(whh[(size_t)row * 896 + col]);
  }
  out[idx] = val;
}

// ---------------- encoder: input projections gi = in @ Wih^T + bih ----------------
__global__ __launch_bounds__(384) void k_gi_enc(
    const float* __restrict__ in, const float* __restrict__ Wih,
    const float* __restrict__ bih, float* __restrict__ out, int K)
{
  __shared__ float in_s[256];
  int tb = blockIdx.x;
  for (int i = threadIdx.x; i < K; i += 384) in_s[i] = in[tb * K + i];
  __syncthreads();
  int row = threadIdx.x;
  float acc = bih[row];
  const float* wr = Wih + row * K;
  for (int k = 0; k < K; ++k) acc += in_s[k] * wr[k];
  out[tb * 384 + row] = acc;
}

// ---------------- encoder: sequential scan, one WG per direction ----------------
__global__ __launch_bounds__(512) void k_scan_enc(
    const float* __restrict__ gi_f, const float* __restrict__ gi_b,
    const float* __restrict__ whh_f, const float* __restrict__ bhh_f,
    const float* __restrict__ whh_b, const float* __restrict__ bhh_b,
    float* __restrict__ c_out)   // (32,4,256)
{
  const int dir = blockIdx.x, tid = threadIdx.x;
  const float* gi  = dir ? gi_b  : gi_f;
  const float* whh = dir ? whh_b : whh_f;
  const float* bhh = dir ? bhh_b : bhh_f;
  __shared__ unsigned short h_s[BATCH][DE + 8];
  __shared__ float gh_s[384][4];
  __shared__ float bhh_s[384];
  for (int i = tid; i < 384; i += 512) bhh_s[i] = bhh[i];
  for (int i = tid; i < BATCH * (DE + 8); i += 512) ((unsigned short*)h_s)[i] = 0;
  __syncthreads();
  for (int s = 0; s < T_M; ++s) {
    int t = dir ? (T_M - 1 - s) : s;
    #pragma unroll
    for (int k3 = 0; k3 < 3; ++k3) {
      int d = tid + 512 * k3;
      int row = d >> 2, b = d & 3;
      const float* wr = whh + row * DE;
      float acc = 0.f;
      for (int j = 0; j < DE; j += 8) {
        float4 w0 = *(const float4*)(wr + j);
        float4 w1 = *(const float4*)(wr + j + 4);
        uint4  hv = *(const uint4*)&h_s[b][j];
        acc += w0.x * blo(hv.x) + w0.y * bhi(hv.x) + w0.z * blo(hv.y) + w0.w * bhi(hv.y);
        acc += w1.x * blo(hv.z) + w1.y * bhi(hv.z) + w1.z * blo(hv.w) + w1.w * bhi(hv.w);
      }
      gh_s[row][b] = acc + bhh_s[row];
    }
    __syncthreads();
    {
      int u = tid >> 2, b = tid & 3;
      const float* git = gi + (t * BATCH + b) * 384;
      float r = sigm(git[u] + gh_s[u][b]);
      float z = sigm(git[DE + u] + gh_s[DE + u][b]);
      float n = tanh_fast(git[2 * DE + u] + r * gh_s[2 * DE + u][b]);
      float hold = b2f(h_s[b][u]);
      float hnew = (1.f - z) * n + z * hold;
      c_out[(t * BATCH + b) * 256 + dir * DE + u] = hnew;
      h_s[b][u] = f2b(hnew);
    }
    __syncthreads();
  }
}

// ---------------- build wav-GRU input X = [embed, upsampled c] (bf16) ----------------
__global__ __launch_bounds__(256) void k_build_X(
    const float* __restrict__ y, const float* __restrict__ E,
    const float* __restrict__ c1, unsigned short* __restrict__ X)
{
  int t = blockIdx.x, c = threadIdx.x;
  int tm = t / 80;
  #pragma unroll
  for (int b = 0; b < BATCH; ++b) {
    float w = (t == 0) ? 0.f : y[(t - 1) * BATCH + b];
    int q = (int)floorf((w + 1.f) * 128.f);
    q = q < 0 ? 0 : (q > 255 ? 255 : q);
    unsigned short* xb = X + (size_t)(t * BATCH + b) * 512;
    xb[c]       = f2b(E[q * 256 + c]);
    xb[256 + c] = f2b(c1[(tm * BATCH + b) * 256 + c]);
  }
}

// ---------------- MFMA GEMM: C(MxN) = act(A(bf16 MxK) @ B(bf16 NxK)^T + bias) -------
// swz=1: write bf16 into wav-GRU packed gi layout [t][G][gate][batch][unit] (96B blocks)
__global__ __launch_bounds__(256) void k_mgemm(
    const unsigned short* __restrict__ A, const unsigned short* __restrict__ B,
    const float* __restrict__ bias, void* __restrict__ C,
    int M, int N, int K, int act, int c_bf16, int swz)
{
  __shared__ unsigned short As[128][40];
  __shared__ unsigned short Bs[128][40];
  const int tid = threadIdx.x;
  const int m0 = blockIdx.x * 128, n0 = blockIdx.y * 128;
  const int lane = tid & 63, wave = tid >> 6;
  const int wy = wave >> 1, wx = wave & 1;
  const int row16 = lane & 15, quad = lane >> 4;
  const int sr = tid >> 1, sc = (tid & 1) * 16;
  f32x4 acc[4][4] = {};
  for (int kt = 0; kt < K; kt += 32) {
    uint4 av  = *(const uint4*)(A + (size_t)(m0 + sr) * K + kt + sc);
    uint4 av2 = *(const uint4*)(A + (size_t)(m0 + sr) * K + kt + sc + 8);
    uint4 bv  = *(const uint4*)(B + (size_t)(n0 + sr) * K + kt + sc);
    uint4 bv2 = *(const uint4*)(B + (size_t)(n0 + sr) * K + kt + sc + 8);
    __syncthreads();
    *(uint4*)&As[sr][sc] = av; *(uint4*)&As[sr][sc + 8] = av2;
    *(uint4*)&Bs[sr][sc] = bv; *(uint4*)&Bs[sr][sc + 8] = bv2;
    __syncthreads();
    bf16x8 af[4], bf[4];
    #pragma unroll
    for (int i = 0; i < 4; ++i) af[i] = *(const bf16x8*)&As[wy * 64 + i * 16 + row16][quad * 8];
    #pragma unroll
    for (int j = 0; j < 4; ++j) bf[j] = *(const bf16x8*)&Bs[wx * 64 + j * 16 + row16][quad * 8];
    #pragma unroll
    for (int i = 0; i < 4; ++i)
      #pragma unroll
      for (int j = 0; j < 4; ++j)
        acc[i][j] = __builtin_amdgcn_mfma_f32_16x16x32_bf16(af[i], bf[j], acc[i][j], 0, 0, 0);
  }
  #pragma unroll
  for (int i = 0; i < 4; ++i) {
    #pragma unroll
    for (int j = 0; j < 4; ++j) {
      int col = n0 + wx * 64 + j * 16 + row16;
      float bs = bias[col];
      #pragma unroll
      for (int r = 0; r < 4; ++r) {
        int row = m0 + wy * 64 + i * 16 + quad * 4 + r;
        float v = acc[i][j][r] + bs;
        if (act) v = gelu_exact(v);
        if (swz) {
          int t = row >> 2, b = row & 3;
          int g = col / 896, rem = col - g * 896;
          int G = rem >> 2, u = rem & 3;
          ((unsigned short*)C)[(size_t)(t * 224 + G) * 48 + g * 16 + b * 4 + u] = f2b(v);
        } else if (c_bf16) {
          ((unsigned short*)C)[(size_t)row * N + col] = f2b(v);
        } else {
          ((float*)C)[(size_t)row * N + col] = v;
        }
      }
    }
  }
}

// ---------------- wav GRU: 28 WGs x 8 waves; every wave polls/computes/publishes -----
// LLC protocol (sc0 sc1 packet stores/loads, tag-in-16B-packet, double buffer).
// Wave owns 4 h-units: 28 MFMAs from 112 VGPRs of pre-swizzled Whh; in-wave finalize.
// gi comes packed per-(t,G) in 96B blocks; h_lds double-buffered -> 1 barrier/step.
__global__ __launch_bounds__(512, 1) void k_wav_rnn(
    const unsigned short* __restrict__ whh_p,  // swizzled (224,28,4,16,8) bf16
    const float* __restrict__ bhh,             // (2688,)
    const unsigned short* __restrict__ gp_,    // packed gi (2560,224,3,4,4) bf16
    unsigned int* __restrict__ hslots,         // 2*896 packets of 16B, zeroed
    unsigned int* __restrict__ O32)            // (10240,448) dwords of bf16 pairs
{
  const int wg = blockIdx.x, tid = threadIdx.x;
  const int lane = tid & 63, wave = tid >> 6;
  const int G = wg * 8 + wave;                 // global 4-unit group

  __shared__ unsigned short h_lds[2][4][912];  // h(t) double buffer, stride 1824B
  __shared__ float phh[8][3][4][4];            // [wave][gate][batch][unit]

  const int r16 = lane & 15, quad = lane >> 4, bb = lane & 3;
  const int fu = (lane >> 2) & 3, fb = lane & 3;   // finalize mapping (lanes 0-15 real)

  // ---- Whh fragments -> VGPRs (28 x bf16x8 = 112 VGPRs), coalesced 16B/lane ----
  bf16x8 wf[28];
  {
    const bf16x8* W8 = (const bf16x8*)whh_p + (size_t)G * 28 * 64;
    #pragma unroll
    for (int kc = 0; kc < 28; ++kc)
      wf[kc] = W8[(kc * 4 + quad) * 16 + r16];
  }

  // ---- per-lane bias + recurrent state ----
  const float br_ = bhh[G * 4 + fu];
  const float bz_ = bhh[896 + G * 4 + fu];
  const float bn_ = bhh[1792 + G * 4 + fu];
  float hprev = 0.f;
  const unsigned short* gl0 = gp_ + (size_t)G * 48 + fb * 4 + fu;
  unsigned short cr = gl0[0], cz = gl0[16], cn = gl0[32];   // gi(0), raw bf16 bits

  // ---- poll slice: wave covers packets [wave*112, wave*112+112) ----
  const int l56 = (lane < 56) ? lane : (lane - 56);
  const int p0 = wave * 112 + l56;
  const int p1 = p0 + 56;
  const int pb0 = p0 / 224, pG0 = p0 - pb0 * 224;
  const int pb1 = p1 / 224, pG1 = p1 - pb1 * 224;

  const unsigned long long base0 = (unsigned long long)hslots;
  const unsigned long long base1 = base0 + 14336ull;

  for (int t = 0; t < T_W; ++t) {
    // ---- poll my 2 packets (tags == t) ----
    const unsigned long long hb = (t & 1) ? base1 : base0;
    unsigned long long a0 = hb + ((unsigned long long)p0 << 4);
    unsigned long long a1 = hb + ((unsigned long long)p1 << 4);
    u32x4 s0, s1;
    const unsigned int tg = (unsigned int)t;
    unsigned int bad;
    do {
      asm volatile(
        "global_load_dwordx4 %0, %2, off sc0 sc1\n"
        "global_load_dwordx4 %1, %3, off sc0 sc1\n"
        "s_waitcnt vmcnt(0)"
        : "=&v"(s0), "=&v"(s1)
        : "v"(a0), "v"(a1)
        : "memory");
      bad = (s0.z ^ tg) | (s1.z ^ tg);
    } while (__any(bad != 0));

    // ---- issue gi(t+1) loads now (raw bf16 bits; consumed at next finalize) ----
    int tn = (t + 1 < T_W) ? (t + 1) : t;
    const unsigned short* gp = gp_ + (size_t)tn * 10752 + G * 48 + fb * 4 + fu;
    unsigned short nr_ = gp[0], nz_ = gp[16], nn_ = gp[32];

    // ---- scatter h(t) into LDS buffer t&1 (lanes < 56; 112 packets per wave) ----
    if (lane < 56) {
      *(uint2*)&h_lds[t & 1][pb0][pG0 * 4] = make_uint2(s0.x, s0.y);
      *(uint2*)&h_lds[t & 1][pb1][pG1 * 4] = make_uint2(s1.x, s1.y);
    }
    __syncthreads();   // single barrier: h(t) fully in LDS

    // ---- 28 MFMAs, 4 interleaved accumulator chains ----
    f32x4 ac0 = {}, ac1 = {}, ac2 = {}, ac3 = {};
    #pragma unroll
    for (int kc = 0; kc < 28; kc += 4) {
      bf16x8 h0 = *(const bf16x8*)&h_lds[t & 1][bb][(kc + 0) * 32 + quad * 8];
      bf16x8 h1 = *(const bf16x8*)&h_lds[t & 1][bb][(kc + 1) * 32 + quad * 8];
      bf16x8 h2 = *(const bf16x8*)&h_lds[t & 1][bb][(kc + 2) * 32 + quad * 8];
      bf16x8 h3 = *(const bf16x8*)&h_lds[t & 1][bb][(kc + 3) * 32 + quad * 8];
      ac0 = __builtin_amdgcn_mfma_f32_16x16x32_bf16(wf[kc + 0], h0, ac0, 0, 0, 0);
      ac1 = __builtin_amdgcn_mfma_f32_16x16x32_bf16(wf[kc + 1], h1, ac1, 0, 0, 0);
      ac2 = __builtin_amdgcn_mfma_f32_16x16x32_bf16(wf[kc + 2], h2, ac2, 0, 0, 0);
      ac3 = __builtin_amdgcn_mfma_f32_16x16x32_bf16(wf[kc + 3], h3, ac3, 0, 0, 0);
    }
    f32x4 ac;
    ac[0] = ac0[0] + ac1[0] + ac2[0] + ac3[0];
    ac[1] = ac0[1] + ac1[1] + ac2[1] + ac3[1];
    ac[2] = ac0[2] + ac1[2] + ac2[2] + ac3[2];
    ac[3] = ac0[3] + ac1[3] + ac2[3] + ac3[3];

    // ---- in-wave transpose via LDS: D[row=quad*4+reg][col=r16] -> phh[v][g][b][u] ----
    if (r16 < 4 && quad < 3)
      *(f32x4*)&phh[wave][quad][r16][0] = ac;
    asm volatile("s_waitcnt lgkmcnt(0)" ::: "memory");   // same-wave DS in-order

    // ---- finalize my 16 h values (lanes 0-15; others duplicate harmlessly) ----
    float pr = phh[wave][0][fb][fu];
    float pz = phh[wave][1][fb][fu];
    float pn = phh[wave][2][fb][fu];
    float r = sigm(b2f(cr) + br_ + pr);
    float z = sigm(b2f(cz) + bz_ + pz);
    float n = tanh_fast(b2f(cn) + bn_ + r * pn);
    float h = (1.f - z) * n + z * hprev;
    hprev = h;
    unsigned int hu = f2b(h);
    cr = nr_; cz = nz_; cn = nn_;

    // ---- publish: lanes 0-3 own packet (batch b = lane) ----
    int b = lane & 3;
    unsigned int u0v = (unsigned int)__shfl((int)hu, 0 + b);
    unsigned int u1v = (unsigned int)__shfl((int)hu, 4 + b);
    unsigned int u2v = (unsigned int)__shfl((int)hu, 8 + b);
    unsigned int u3v = (unsigned int)__shfl((int)hu, 12 + b);
    if (lane < 4) {
      u32x4 pkt;
      pkt.x = (u0v & 0xffffu) | (u1v << 16);
      pkt.y = (u2v & 0xffffu) | (u3v << 16);
      pkt.z = (unsigned int)(t + 1);
      pkt.w = 0u;
      unsigned long long sa = (((t + 1) & 1) ? base1 : base0)
                            + (unsigned long long)((b * 224 + G) << 4);
      asm volatile("global_store_dwordx4 %0, %1, off sc0 sc1"
                   :: "v"(sa), "v"(pkt) : "memory");
      *(uint2*)(O32 + (size_t)(t * 4 + b) * 448 + G * 2) = make_uint2(pkt.x, pkt.y);
    }
  }
}

// ---------------- NLL ----------------
__global__ __launch_bounds__(256) void k_nll(
    const float* __restrict__ logits, const float* __restrict__ y,
    float* __restrict__ acc)
{
  int wid = threadIdx.x >> 6, lane = threadIdx.x & 63;
  int row = blockIdx.x * 4 + wid;
  const float* lr = logits + (size_t)row * 256;
  float v0 = lr[lane], v1 = lr[lane + 64], v2 = lr[lane + 128], v3 = lr[lane + 192];
  float mx = fmaxf(fmaxf(v0, v1), fmaxf(v2, v3));
  for (int off = 32; off > 0; off >>= 1) mx = fmaxf(mx, __shfl_xor(mx, off));
  float se = __expf(v0 - mx) + __expf(v1 - mx) + __expf(v2 - mx) + __expf(v3 - mx);
  for (int off = 32; off > 0; off >>= 1) se += __shfl_xor(se, off);
  if (lane == 0) {
    float w = y[row];
    int q = (int)floorf((w + 1.f) * 128.f);
    q = q < 0 ? 0 : (q > 255 ? 255 : q);
    float contrib = (logf(se) + mx) - lr[q];
    atomicAdd(acc, contrib);
  }
}

__global__ void k_final(const float* __restrict__ acc, float* __restrict__ out) {
  out[0] = acc[0] * (1.f / 10240.f);
}

// ---------------- host ----------------
extern "C" void kernel_launch(void* const* d_in, const int* in_sizes, int n_in,
                              void* d_out, int out_size, void* d_ws, size_t ws_size,
                              hipStream_t stream)
{
  const float* x       = (const float*)d_in[0];
  const float* y       = (const float*)d_in[1];
  const float* m0f_Wih = (const float*)d_in[2];
  const float* m0f_Whh = (const float*)d_in[3];
  const float* m0f_bih = (const float*)d_in[4];
  const float* m0f_bhh = (const float*)d_in[5];
  const float* m0b_Wih = (const float*)d_in[6];
  const float* m0b_Whh = (const float*)d_in[7];
  const float* m0b_bih = (const float*)d_in[8];
  const float* m0b_bhh = (const float*)d_in[9];
  const float* m1f_Wih = (const float*)d_in[10];
  const float* m1f_Whh = (const float*)d_in[11];
  const float* m1f_bih = (const float*)d_in[12];
  const float* m1f_bhh = (const float*)d_in[13];
  const float* m1b_Wih = (const float*)d_in[14];
  const float* m1b_Whh = (const float*)d_in[15];
  const float* m1b_bih = (const float*)d_in[16];
  const float* m1b_bhh = (const float*)d_in[17];
  const float* w_Wih   = (const float*)d_in[18];
  const float* w_Whh   = (const float*)d_in[19];
  const float* w_bih   = (const float*)d_in[20];
  const float* w_bhh   = (const float*)d_in[21];
  const float* Wp      = (const float*)d_in[22];
  const float* bp      = (const float*)d_in[23];
  const float* E       = (const float*)d_in[24];
  const float* Wd      = (const float*)d_in[25];
  const float* bd      = (const float*)d_in[26];

  char* ws = (char*)d_ws;
  size_t off = 0;
  auto alloc = [&](size_t bytes) -> void* {
    void* p = ws + off;
    off += (bytes + 255) & ~(size_t)255;
    return p;
  };
  // misc (zeroed each launch): nll acc + h packet buffers
  float*        nacc   = (float*)alloc(64);
  unsigned int* hslots = (unsigned int*)alloc(2 * 896 * 16);
  size_t misc_bytes = off;

  float* c0   = (float*)alloc((size_t)32 * 4 * 256 * 4);
  float* c1   = (float*)alloc((size_t)32 * 4 * 256 * 4);
  float* gi0f = (float*)alloc((size_t)32 * 4 * 384 * 4);
  float* gi0b = (float*)alloc((size_t)32 * 4 * 384 * 4);
  float* gi1f = (float*)alloc((size_t)32 * 4 * 384 * 4);
  float* gi1b = (float*)alloc((size_t)32 * 4 * 384 * 4);
  unsigned short* X     = (unsigned short*)alloc((size_t)10240 * 512 * 2);
  unsigned short* gpack = (unsigned short*)alloc((size_t)2560 * 224 * 48 * 2);
  unsigned int*   O32   = (unsigned int*)alloc((size_t)10240 * 448 * 4);
  unsigned short* O2    = (unsigned short*)alloc((size_t)10240 * 512 * 2);
  float*          LG    = (float*)alloc((size_t)10240 * 256 * 4);
  unsigned short* Wih_b = (unsigned short*)alloc((size_t)2688 * 512 * 2);
  unsigned short* Whh_p = (unsigned short*)alloc((size_t)224 * 28 * 512 * 2);
  unsigned short* Wp_b  = (unsigned short*)alloc((size_t)512 * 896 * 2);
  unsigned short* Wd_b  = (unsigned short*)alloc((size_t)256 * 512 * 2);

  hipMemsetAsync(d_ws, 0, misc_bytes, stream);

  // weight preprocessing
  k_cast<<<(2688 * 512 + 255) / 256, 256, 0, stream>>>(w_Wih, Wih_b, 2688 * 512);
  k_cast<<<(512 * 896 + 255) / 256, 256, 0, stream>>>(Wp, Wp_b, 512 * 896);
  k_cast<<<(256 * 512 + 255) / 256, 256, 0, stream>>>(Wd, Wd_b, 256 * 512);
  k_prep_whh<<<(224 * 28 * 512 + 255) / 256, 256, 0, stream>>>(w_Whh, Whh_p);

  // encoder
  k_gi_enc<<<128, 384, 0, stream>>>(x, m0f_Wih, m0f_bih, gi0f, 80);
  k_gi_enc<<<128, 384, 0, stream>>>(x, m0b_Wih, m0b_bih, gi0b, 80);
  k_scan_enc<<<2, 512, 0, stream>>>(gi0f, gi0b, m0f_Whh, m0f_bhh, m0b_Whh, m0b_bhh, c0);
  k_gi_enc<<<128, 384, 0, stream>>>(c0, m1f_Wih, m1f_bih, gi1f, 256);
  k_gi_enc<<<128, 384, 0, stream>>>(c0, m1b_Wih, m1b_bih, gi1b, 256);
  k_scan_enc<<<2, 512, 0, stream>>>(gi1f, gi1b, m1f_Whh, m1f_bhh, m1b_Whh, m1b_bhh, c1);

  // wav input + precomputed input projection (includes bih), written packed
  k_build_X<<<2560, 256, 0, stream>>>(y, E, c1, X);
  k_mgemm<<<dim3(80, 21), 256, 0, stream>>>(X, Wih_b, w_bih, (void*)gpack,
                                            10240, 2688, 512, 0, 1, 1);

  // recurrent wav GRU (persistent, tag-based LLC sync; 28 WGs, 8 waves each)
  k_wav_rnn<<<NWG, 512, 0, stream>>>(Whh_p, w_bhh, gpack, hslots, O32);

  // head
  k_mgemm<<<dim3(80, 4), 256, 0, stream>>>((const unsigned short*)O32, Wp_b, bp,
                                           (void*)O2, 10240, 512, 896, 1, 1, 0);
  k_mgemm<<<dim3(80, 2), 256, 0, stream>>>(O2, Wd_b, bd, (void*)LG,
                                           10240, 256, 512, 0, 0, 0);
  k_nll<<<2560, 256, 0, stream>>>(LG, y, nacc);
  k_final<<<1, 1, 0, stream>>>(nacc, (float*)d_out);
}